// Round 3
// baseline (9628.869 us; speedup 1.0000x reference)
//
#include <hip/hip_runtime.h>
#include <cstdint>

// ---------------------------------------------------------------------------
// DND lookup: A=8, N=50000, D=64, B=256, K=50.
//   K1: fp32 GEMM filter d2 <= |q|^2 + 25 -> per-(a,b) candidate lists.
//   K2: histogram-superset (~60 survivors) -> re-score with a BIT-EXACT
//       replica of the numpy-fp32 reference arithmetic:
//         d2  = fl(fl(qsq_r8 + ksq_r8) - 2*fmaf_chain(q,k))
//         qsq/ksq: numpy pairwise_sum r[8] algorithm over rounded squares
//         dot: sequential k-ascending FMA chain (BLAS microkernel order)
//       rank lex (d2, idx) = lax.top_k tie semantics; scores = r8 pairwise
//       over rounded (q-k)^2; value = pairwise(n=50 w/ remainder) sums.
//   K3: max / first-argmax.
// Output layout (flat fp32): [0,256) max | [256,512) action | [512,2560)
// values_all | [2560,104960) idx | [104960,207360) scores.
// ---------------------------------------------------------------------------

#define A_N 8
#define N_N 50000
#define D_N 64
#define B_N 256
#define K_N 50

constexpr int   BQ = 128;
constexpr int   BN = 128;
constexpr int   LDP = D_N + 4;
constexpr int   NT = (N_N + BN - 1) / BN;  // 391
constexpr int   SL = 49;                   // grid 49*2*8 = 784 blocks
constexpr int   CAPMAX = 4096;
constexpr float TMARG = 25.0f;

constexpr int OFF_MAX = 0;
constexpr int OFF_ACT = 256;
constexpr int OFF_VAL = 512;
constexpr int OFF_IDX = 2560;
constexpr int OFF_SC  = 104960;

// ---------------------------------------------------------------------------
// numpy pairwise_sum replicas (n<=128 scalar r[8] path; exact rounding via
// _rn intrinsics so hipcc cannot contract/reassociate).
// ---------------------------------------------------------------------------
__device__ __forceinline__ float np_tree8(const float r[8])
{
    return __fadd_rn(__fadd_rn(__fadd_rn(r[0], r[1]), __fadd_rn(r[2], r[3])),
                     __fadd_rn(__fadd_rn(r[4], r[5]), __fadd_rn(r[6], r[7])));
}

// sum_{d<64} fl(a[d]^2), numpy order
__device__ __forceinline__ float np_sumsq64(const float* __restrict__ a)
{
    float r[8];
#pragma unroll
    for (int j = 0; j < 8; ++j) r[j] = __fmul_rn(a[j], a[j]);
    for (int i = 8; i < 64; i += 8)
#pragma unroll
        for (int j = 0; j < 8; ++j)
            r[j] = __fadd_rn(r[j], __fmul_rn(a[i + j], a[i + j]));
    return np_tree8(r);
}

// sum_{k<50} a[k], numpy order (tree over first 48, then remainder 48,49)
__device__ __forceinline__ float np_sum50(const float* __restrict__ a)
{
    float r[8];
#pragma unroll
    for (int j = 0; j < 8; ++j) r[j] = a[j];
    for (int i = 8; i < 48; i += 8)
#pragma unroll
        for (int j = 0; j < 8; ++j) r[j] = __fadd_rn(r[j], a[i + j]);
    float res = np_tree8(r);
    res = __fadd_rn(res, a[48]);
    res = __fadd_rn(res, a[49]);
    return res;
}

// ---------------------------------------------------------------------------
// K1: tiled fp32 distance GEMM + threshold filter (unchanged from R1/R2 —
// its role is only a safe superset; margin 25 >> 1e-4 noise).
// ---------------------------------------------------------------------------
__global__ __launch_bounds__(256, 2)
void dnd_k1(const float* __restrict__ query, const float* __restrict__ keys,
            int* __restrict__ cnt, uint2* __restrict__ cand, int cap)
{
    __shared__ __align__(16) float qs[BQ][LDP];
    __shared__ __align__(16) float ks[BN][LDP];
    __shared__ float qsq[BQ];
    __shared__ float ksq[BN];
    __shared__ float qhalf[BQ][2];
    __shared__ float khalf[BN][2];

    const int a   = blockIdx.z;
    const int q0  = blockIdx.y * BQ;
    const int sl  = blockIdx.x;
    const int tid = threadIdx.x;
    const int tx  = tid & 15;
    const int ty  = tid >> 4;

    {
        const int r = tid >> 1, h = tid & 1;
        const float4* src = (const float4*)(query + (size_t)(q0 + r) * D_N + h * 32);
        float4* dst = (float4*)(&qs[r][h * 32]);
        float ps = 0.f;
#pragma unroll
        for (int i = 0; i < 8; ++i) {
            float4 v = src[i];
            dst[i] = v;
            ps += v.x * v.x + v.y * v.y + v.z * v.z + v.w * v.w;
        }
        qhalf[r][h] = ps;
    }
    __syncthreads();
    if (tid < BQ) qsq[tid] = qhalf[tid][0] + qhalf[tid][1];

    for (int t = sl; t < NT; t += SL) {
        const int n0 = t * BN;
        __syncthreads();
        {
            const int r = tid >> 1, h = tid & 1;
            int n = n0 + r; if (n > N_N - 1) n = N_N - 1;
            const float4* src = (const float4*)(keys + ((size_t)a * N_N + n) * D_N + h * 32);
            float4* dst = (float4*)(&ks[r][h * 32]);
            float ps = 0.f;
#pragma unroll
            for (int i = 0; i < 8; ++i) {
                float4 v = src[i];
                dst[i] = v;
                ps += v.x * v.x + v.y * v.y + v.z * v.z + v.w * v.w;
            }
            khalf[r][h] = ps;
        }
        __syncthreads();
        if (tid < BN)
            ksq[tid] = (n0 + tid < N_N) ? (khalf[tid][0] + khalf[tid][1])
                                        : __builtin_huge_valf();
        __syncthreads();

        float acc[8][8];
#pragma unroll
        for (int j = 0; j < 8; ++j)
#pragma unroll
            for (int i = 0; i < 8; ++i) acc[j][i] = 0.f;

#pragma unroll
        for (int k4 = 0; k4 < 16; ++k4) {
            float4 kv[8];
#pragma unroll
            for (int i = 0; i < 8; ++i)
                kv[i] = *(const float4*)(&ks[tx + i * 16][k4 * 4]);
#pragma unroll
            for (int j = 0; j < 8; ++j) {
                const float4 qv = *(const float4*)(&qs[ty + j * 16][k4 * 4]);
#pragma unroll
                for (int i = 0; i < 8; ++i) {
                    acc[j][i] = fmaf(qv.x, kv[i].x, acc[j][i]);
                    acc[j][i] = fmaf(qv.y, kv[i].y, acc[j][i]);
                    acc[j][i] = fmaf(qv.z, kv[i].z, acc[j][i]);
                    acc[j][i] = fmaf(qv.w, kv[i].w, acc[j][i]);
                }
            }
        }

#pragma unroll
        for (int j = 0; j < 8; ++j) {
            const int qr = ty + j * 16;
            const int b  = q0 + qr;
            const float qq = qsq[qr];
            const float T  = qq + TMARG;
#pragma unroll
            for (int i = 0; i < 8; ++i) {
                const int   nn = n0 + tx + i * 16;
                const float d2 = qq + ksq[tx + i * 16] - 2.0f * acc[j][i];
                if (d2 <= T) {
                    const int p = atomicAdd(&cnt[a * B_N + b], 1);
                    if (p < cap) {
                        uint2 e; e.x = __float_as_uint(d2); e.y = (unsigned)nn;
                        cand[(size_t)(a * B_N + b) * cap + p] = e;
                    }
                }
            }
        }
    }
}

// ---------------------------------------------------------------------------
// K2: per-(a,b) np-fp32-replica top-50 + outputs. Grid (B, A), 256 threads.
// ---------------------------------------------------------------------------
__global__ __launch_bounds__(256, 2)
void dnd_k2(const float* __restrict__ query, const float* __restrict__ keys,
            const float* __restrict__ values,
            const int* __restrict__ cnt, const uint2* __restrict__ cand, int cap,
            float* __restrict__ vall, float* __restrict__ dout)
{
    __shared__ __align__(16) float qrow[D_N];
    __shared__ float cd[CAPMAX];
    __shared__ int   cn[CAPMAX];
    __shared__ int   hist[256];
    __shared__ float sdf[512];
    __shared__ int   sn[512];
    __shared__ int   wn[K_N];
    __shared__ float wsc[K_N];   // replica scores (dist)
    __shared__ float wgv[K_N];   // gathered values
    __shared__ int   nsurv;
    __shared__ int   bstar;
    __shared__ float sqsq;       // fast qq for binning only
    __shared__ float qsq_np;     // numpy-replica |q|^2

    const int b   = blockIdx.x;
    const int a   = blockIdx.y;
    const int ab  = a * B_N + b;
    const int tid = threadIdx.x;

    if (tid < D_N) qrow[tid] = query[(size_t)b * D_N + tid];
    hist[tid & 255] = 0;
    if (tid == 0) nsurv = 0;
    if (tid < K_N) wn[tid] = 0;      // safety
    __syncthreads();
    if (tid < 64) {
        float v = qrow[tid];
        float s = v * v;
#pragma unroll
        for (int m = 1; m < 64; m <<= 1) s += __shfl_xor(s, m, 64);
        if (tid == 0) sqsq = s;
    }
    if (tid == 0) qsq_np = np_sumsq64(qrow);   // exact numpy order
    __syncthreads();

    int c = cnt[ab]; if (c > cap) c = cap; if (c > CAPMAX) c = CAPMAX;
    const float qq = sqsq;

    // phase A: stage candidates + histogram of (K1 d2 - qq), bins 0.25 wide
    for (int i = tid; i < c; i += 256) {
        uint2 e = cand[(size_t)ab * cap + i];
        float d = __uint_as_float(e.x);
        cd[i] = d; cn[i] = (int)e.y;
        int bin = (int)((d - qq + 40.f) * 4.f);
        bin = bin < 0 ? 0 : (bin > 255 ? 255 : bin);
        atomicAdd(&hist[bin], 1);
    }
    __syncthreads();
    if (tid == 0) {
        const int need = c < K_N ? c : K_N;
        int cum = 0, bs = 255;
        for (int i = 0; i < 256; ++i) { cum += hist[i]; if (cum >= need) { bs = i; break; } }
        bstar = bs;
    }
    __syncthreads();
    const int bs = bstar + 1;   // +0.25 d2 margin: superset robust to fp32 noise

    // phase B: compact survivor indices (expected ~60)
    for (int i = tid; i < c; i += 256) {
        float d = cd[i];
        int bin = (int)((d - qq + 40.f) * 4.f);
        bin = bin < 0 ? 0 : (bin > 255 ? 255 : bin);
        if (bin <= bs) {
            int p = atomicAdd(&nsurv, 1);
            if (p < 512) sn[p] = cn[i];
        }
    }
    __syncthreads();
    int c2 = nsurv; if (c2 > 512) c2 = 512;

    // phase C: np-replica fp32 d2 per survivor:
    //   d2 = fl( fl(qsq_np + ksq_np) - 2*dotchain )   (2x exact binade shift)
    const float qn = qsq_np;
    for (int i = tid; i < c2; i += 256) {
        const int n = sn[i];
        const float4* kr = (const float4*)(keys + ((size_t)a * N_N + n) * D_N);
        const float4* qr = (const float4*)qrow;
        float r[8];
#pragma unroll
        for (int j = 0; j < 8; ++j) r[j] = 0.f;
        float dot = 0.f;
#pragma unroll
        for (int cch = 0; cch < 16; ++cch) {
            float4 kk = kr[cch]; float4 qv = qr[cch];
            const int j0 = (cch & 1) * 4;
            // d ascending: ksq r[j] accumulation in numpy order (j = d & 7)
            if (cch < 2) {
                r[j0 + 0] = __fmul_rn(kk.x, kk.x);
                r[j0 + 1] = __fmul_rn(kk.y, kk.y);
                r[j0 + 2] = __fmul_rn(kk.z, kk.z);
                r[j0 + 3] = __fmul_rn(kk.w, kk.w);
            } else {
                r[j0 + 0] = __fadd_rn(r[j0 + 0], __fmul_rn(kk.x, kk.x));
                r[j0 + 1] = __fadd_rn(r[j0 + 1], __fmul_rn(kk.y, kk.y));
                r[j0 + 2] = __fadd_rn(r[j0 + 2], __fmul_rn(kk.z, kk.z));
                r[j0 + 3] = __fadd_rn(r[j0 + 3], __fmul_rn(kk.w, kk.w));
            }
            // BLAS microkernel: sequential k-ascending FMA chain from zero
            dot = __fmaf_rn(qv.x, kk.x, dot);
            dot = __fmaf_rn(qv.y, kk.y, dot);
            dot = __fmaf_rn(qv.z, kk.z, dot);
            dot = __fmaf_rn(qv.w, kk.w, dot);
        }
        const float ksq = np_tree8(r);
        sdf[i] = __fsub_rn(__fadd_rn(qn, ksq), __fmul_rn(2.0f, dot));
    }
    __syncthreads();

    // phase D: lexicographic (d2, idx) rank — lax.top_k tie semantics
    for (int i = tid; i < c2; i += 256) {
        const float di = sdf[i]; const int ni = sn[i];
        int rank = 0;
        for (int j = 0; j < c2; ++j) {
            const float dj = sdf[j]; const int nj = sn[j];
            rank += (dj < di || (dj == di && nj < ni)) ? 1 : 0;
        }
        if (rank < K_N) wn[rank] = ni;
    }
    __syncthreads();

    // phase E1: replica scores dist = np_pairwise( fl(fl(q-k)^2) ) + gather v
    if (tid < K_N) {
        const int n = wn[tid];
        const float* kr = keys + ((size_t)a * N_N + n) * D_N;
        float r[8];
#pragma unroll
        for (int j = 0; j < 8; ++j) {
            float d = __fsub_rn(qrow[j], kr[j]);
            r[j] = __fmul_rn(d, d);
        }
        for (int i = 8; i < 64; i += 8)
#pragma unroll
            for (int j = 0; j < 8; ++j) {
                float d = __fsub_rn(qrow[i + j], kr[i + j]);
                r[j] = __fadd_rn(r[j], __fmul_rn(d, d));
            }
        const float dist = np_tree8(r);
        wsc[tid] = dist;
        wgv[tid] = values[(size_t)a * N_N + n];
        dout[OFF_IDX + (size_t)(b * A_N + a) * K_N + tid] = (float)n;
        dout[OFF_SC  + (size_t)(b * A_N + a) * K_N + tid] = dist;
    }
    __syncthreads();

    // phase E2: replica weighted value (numpy n=50 pairwise + remainder)
    if (tid == 0) {
        float w[K_N], wv[K_N];
#pragma unroll
        for (int k = 0; k < K_N; ++k) {
            w[k]  = __fdiv_rn(1.0f, __fadd_rn(wsc[k], 0.001f));
            wv[k] = __fmul_rn(w[k], wgv[k]);
        }
        const float s1 = np_sum50(w);
        const float s2 = np_sum50(wv);
        const float out = __fdiv_rn(s2, s1);
        vall[(size_t)b * A_N + a] = out;
        dout[OFF_VAL + b * A_N + a] = out;
    }
}

// ---------------------------------------------------------------------------
// K3: max / first-argmax over actions.
// ---------------------------------------------------------------------------
__global__ void dnd_k3(const float* __restrict__ vall, float* __restrict__ dout)
{
    const int b = threadIdx.x;
    float best = -__builtin_huge_valf(); int bi = 0;
#pragma unroll
    for (int a = 0; a < A_N; ++a) {
        const float v = vall[b * A_N + a];
        if (v > best) { best = v; bi = a; }
    }
    dout[OFF_MAX + b] = best;
    dout[OFF_ACT + b] = (float)bi;
}

extern "C" void kernel_launch(void* const* d_in, const int* in_sizes, int n_in,
                              void* d_out, int out_size, void* d_ws, size_t ws_size,
                              hipStream_t stream)
{
    (void)in_sizes; (void)n_in; (void)out_size;
    const float* query  = (const float*)d_in[0];
    const float* keys   = (const float*)d_in[1];
    const float* values = (const float*)d_in[2];
    float* dout = (float*)d_out;

    char*  ws   = (char*)d_ws;
    int*   cnt  = (int*)ws;                  // 2048 * 4 B
    float* vall = (float*)(ws + 8192);       // 2048 * 4 B
    uint2* cand = (uint2*)(ws + 16384);      // 2048 * cap * 8 B

    int cap = CAPMAX;
    if (ws_size > 16384) {
        size_t avail = (ws_size - 16384) / ((size_t)A_N * B_N * 8);
        if ((size_t)cap > avail) cap = (int)avail;
    }
    if (cap < 1) cap = 1;

    hipMemsetAsync(cnt, 0, A_N * B_N * sizeof(int), stream);
    dim3 g1(SL, 2, A_N);
    dnd_k1<<<g1, 256, 0, stream>>>(query, keys, cnt, cand, cap);
    dim3 g2(B_N, A_N);
    dnd_k2<<<g2, 256, 0, stream>>>(query, keys, values, cnt, cand, cap, vall, dout);
    dnd_k3<<<1, 256, 0, stream>>>(vall, dout);
}

// Round 4
// 749.597 us; speedup vs baseline: 12.8454x; 12.8454x over previous
//
#include <hip/hip_runtime.h>
#include <cstdint>

// ---------------------------------------------------------------------------
// DND lookup: A=8, N=50000, D=64, B=256, K=50.
//   K0: precompute row square-sums qsq[256], ksq[8*50000] (filter precision).
//   K1: fp32 GEMM filter d2 = qsq + ksq - 2 q.k <= qsq + 25 -> candidate
//       lists. Register-pressure-safe rewrite of R3 (R3 spilled acc to
//       scratch: 17.4 GB FETCH, 2% VALU, 9.6 ms):
//         - global_load_lds width-16 staging (no staging VGPRs, contiguous
//           unpadded 32 KB tiles)
//         - #pragma unroll 1 k4-loop (no scheduler live-range explosion)
//         - per-lane k-slice rotation kk4=((k4+tx)&15)*4 for bank balance
//   K2: histogram-superset -> bit-exact numpy-fp32-replica re-score/rank
//       (UNCHANGED from the passing R3 kernel).
//   K3: max / first-argmax.
// Output layout (flat fp32): [0,256) max | [256,512) action | [512,2560)
// values_all | [2560,104960) idx | [104960,207360) scores.
// ---------------------------------------------------------------------------

#define A_N 8
#define N_N 50000
#define D_N 64
#define B_N 256
#define K_N 50

constexpr int   BQ = 128;
constexpr int   BN = 128;
constexpr int   NT = (N_N + BN - 1) / BN;  // 391
constexpr int   SL = 49;                   // grid 49*2*8 = 784 blocks
constexpr int   CAPMAX = 4096;
constexpr float TMARG = 25.0f;

constexpr int OFF_MAX = 0;
constexpr int OFF_ACT = 256;
constexpr int OFF_VAL = 512;
constexpr int OFF_IDX = 2560;
constexpr int OFF_SC  = 104960;

// workspace layout (bytes)
constexpr size_t WS_CNT  = 0;          // 2048 * 4
constexpr size_t WS_VALL = 8192;       // 2048 * 4
constexpr size_t WS_QSQ  = 16384;      // 256 * 4
constexpr size_t WS_KSQ  = 17408;      // 400000 * 4
constexpr size_t WS_CAND = 1617920;    // 2048 * cap * 8

// async global -> LDS, 16 B per lane (dest = wave-uniform base + lane*16)
__device__ __forceinline__ void async16(void* lds, const void* g)
{
    __builtin_amdgcn_global_load_lds(
        (const __attribute__((address_space(1))) void*)g,
        (__attribute__((address_space(3))) void*)lds, 16, 0, 0);
}

// ---------------------------------------------------------------------------
// numpy pairwise_sum replicas (bit-exact via _rn intrinsics) — used by K2.
// ---------------------------------------------------------------------------
__device__ __forceinline__ float np_tree8(const float r[8])
{
    return __fadd_rn(__fadd_rn(__fadd_rn(r[0], r[1]), __fadd_rn(r[2], r[3])),
                     __fadd_rn(__fadd_rn(r[4], r[5]), __fadd_rn(r[6], r[7])));
}

__device__ __forceinline__ float np_sumsq64(const float* __restrict__ a)
{
    float r[8];
#pragma unroll
    for (int j = 0; j < 8; ++j) r[j] = __fmul_rn(a[j], a[j]);
    for (int i = 8; i < 64; i += 8)
#pragma unroll
        for (int j = 0; j < 8; ++j)
            r[j] = __fadd_rn(r[j], __fmul_rn(a[i + j], a[i + j]));
    return np_tree8(r);
}

__device__ __forceinline__ float np_sum50(const float* __restrict__ a)
{
    float r[8];
#pragma unroll
    for (int j = 0; j < 8; ++j) r[j] = a[j];
    for (int i = 8; i < 48; i += 8)
#pragma unroll
        for (int j = 0; j < 8; ++j) r[j] = __fadd_rn(r[j], a[i + j]);
    float res = np_tree8(r);
    res = __fadd_rn(res, a[48]);
    res = __fadd_rn(res, a[49]);
    return res;
}

// ---------------------------------------------------------------------------
// K0: row square-sums (filter precision only).
// ---------------------------------------------------------------------------
__global__ __launch_bounds__(256)
void dnd_k0(const float* __restrict__ query, const float* __restrict__ keys,
            float* __restrict__ qsq_g, float* __restrict__ ksq_g)
{
    const int r = blockIdx.x * 256 + threadIdx.x;
    if (r >= A_N * N_N + B_N) return;
    const bool isk = r < A_N * N_N;
    const float4* s4 = (const float4*)(isk ? (keys + (size_t)r * D_N)
                                           : (query + (size_t)(r - A_N * N_N) * D_N));
    float s = 0.f;
#pragma unroll
    for (int i = 0; i < 16; ++i) {
        float4 v = s4[i];
        s += v.x * v.x + v.y * v.y + v.z * v.z + v.w * v.w;
    }
    if (isk) ksq_g[r] = s; else qsq_g[r - A_N * N_N] = s;
}

// ---------------------------------------------------------------------------
// K1: tiled fp32 distance GEMM + threshold filter. 128q x 128n block tile,
// 8x8 thread tile. Target ~120 VGPR, zero scratch.
// ---------------------------------------------------------------------------
__global__ __launch_bounds__(256, 2)
void dnd_k1(const float* __restrict__ query, const float* __restrict__ keys,
            const float* __restrict__ qsq_g, const float* __restrict__ ksq_g,
            int* __restrict__ cnt, uint2* __restrict__ cand, int cap)
{
    __shared__ __align__(16) float qs[BQ * D_N];   // 32 KB contiguous
    __shared__ __align__(16) float ks[BN * D_N];   // 32 KB contiguous
    __shared__ float qsqs[BQ];
    __shared__ float ksqs[BN];

    const int a   = blockIdx.z;
    const int q0  = blockIdx.y * BQ;
    const int sl  = blockIdx.x;
    const int tid = threadIdx.x;
    const int tx  = tid & 15;
    const int ty  = tid >> 4;

    // stage all 128 q rows (contiguous 32 KB) — async, no VGPRs
    {
        const char* gq = (const char*)(query + (size_t)q0 * D_N);
#pragma unroll
        for (int i = 0; i < 8; ++i) {
            const int off = i * 4096 + tid * 16;
            async16((char*)qs + off, gq + off);
        }
    }
    if (tid < BQ) qsqs[tid] = qsq_g[q0 + tid];

    for (int t = sl; t < NT; t += SL) {
        const int n0     = t * BN;
        const int nbytes = (N_N - n0 < BN ? N_N - n0 : BN) * (D_N * 4); // mult of 1024
        __syncthreads();   // prev-iter readers done; drains pending async (incl. qs)
        {
            const char* gk = (const char*)(keys + ((size_t)a * N_N + n0) * D_N);
#pragma unroll
            for (int i = 0; i < 8; ++i) {
                const int off = i * 4096 + tid * 16;
                if (off < nbytes)                      // wave-uniform (1 KB granules)
                    async16((char*)ks + off, gk + off);
            }
        }
        if (tid < BN) {
            const int n = n0 + tid;
            ksqs[tid] = (n < N_N) ? ksq_g[(size_t)a * N_N + n]
                                  : __builtin_huge_valf();
        }
        __syncthreads();   // async ks + ksqs visible

        float acc[8][8];
#pragma unroll
        for (int j = 0; j < 8; ++j)
#pragma unroll
            for (int i = 0; i < 8; ++i) acc[j][i] = 0.f;

#pragma unroll 1           // keep body small: no cross-k4 live-range inflation
        for (int k4 = 0; k4 < 16; ++k4) {
            const int kk4 = ((k4 + tx) & 15) * 4;   // per-lane k-slice rotation
            float4 kv[8];
#pragma unroll
            for (int i = 0; i < 8; ++i)
                kv[i] = *(const float4*)&ks[(tx + i * 16) * D_N + kk4];
#pragma unroll
            for (int j = 0; j < 8; ++j) {
                const float4 qv = *(const float4*)&qs[(ty + j * 16) * D_N + kk4];
#pragma unroll
                for (int i = 0; i < 8; ++i) {
                    acc[j][i] = fmaf(qv.x, kv[i].x, acc[j][i]);
                    acc[j][i] = fmaf(qv.y, kv[i].y, acc[j][i]);
                    acc[j][i] = fmaf(qv.z, kv[i].z, acc[j][i]);
                    acc[j][i] = fmaf(qv.w, kv[i].w, acc[j][i]);
                }
            }
        }

        // epilogue: filter d2 <= qq + TMARG, append candidates
#pragma unroll
        for (int j = 0; j < 8; ++j) {
            const int qr = ty + j * 16;
            const int b  = q0 + qr;
            const float qq = qsqs[qr];
            const float T  = qq + TMARG;
#pragma unroll
            for (int i = 0; i < 8; ++i) {
                const float d2 = qq + ksqs[tx + i * 16] - 2.0f * acc[j][i];
                if (d2 <= T) {                    // inf/NaN tail never passes
                    const int p = atomicAdd(&cnt[a * B_N + b], 1);
                    if (p < cap) {
                        uint2 e; e.x = __float_as_uint(d2);
                        e.y = (unsigned)(n0 + tx + i * 16);
                        cand[(size_t)(a * B_N + b) * cap + p] = e;
                    }
                }
            }
        }
    }
}

// ---------------------------------------------------------------------------
// K2: per-(a,b) np-fp32-replica top-50 + outputs (UNCHANGED from passing R3).
// ---------------------------------------------------------------------------
__global__ __launch_bounds__(256, 2)
void dnd_k2(const float* __restrict__ query, const float* __restrict__ keys,
            const float* __restrict__ values,
            const int* __restrict__ cnt, const uint2* __restrict__ cand, int cap,
            float* __restrict__ vall, float* __restrict__ dout)
{
    __shared__ __align__(16) float qrow[D_N];
    __shared__ float cd[CAPMAX];
    __shared__ int   cn[CAPMAX];
    __shared__ int   hist[256];
    __shared__ float sdf[512];
    __shared__ int   sn[512];
    __shared__ int   wn[K_N];
    __shared__ float wsc[K_N];
    __shared__ float wgv[K_N];
    __shared__ int   nsurv;
    __shared__ int   bstar;
    __shared__ float sqsq;
    __shared__ float qsq_np;

    const int b   = blockIdx.x;
    const int a   = blockIdx.y;
    const int ab  = a * B_N + b;
    const int tid = threadIdx.x;

    if (tid < D_N) qrow[tid] = query[(size_t)b * D_N + tid];
    hist[tid & 255] = 0;
    if (tid == 0) nsurv = 0;
    if (tid < K_N) wn[tid] = 0;
    __syncthreads();
    if (tid < 64) {
        float v = qrow[tid];
        float s = v * v;
#pragma unroll
        for (int m = 1; m < 64; m <<= 1) s += __shfl_xor(s, m, 64);
        if (tid == 0) sqsq = s;
    }
    if (tid == 0) qsq_np = np_sumsq64(qrow);
    __syncthreads();

    int c = cnt[ab]; if (c > cap) c = cap; if (c > CAPMAX) c = CAPMAX;
    const float qq = sqsq;

    for (int i = tid; i < c; i += 256) {
        uint2 e = cand[(size_t)ab * cap + i];
        float d = __uint_as_float(e.x);
        cd[i] = d; cn[i] = (int)e.y;
        int bin = (int)((d - qq + 40.f) * 4.f);
        bin = bin < 0 ? 0 : (bin > 255 ? 255 : bin);
        atomicAdd(&hist[bin], 1);
    }
    __syncthreads();
    if (tid == 0) {
        const int need = c < K_N ? c : K_N;
        int cum = 0, bs = 255;
        for (int i = 0; i < 256; ++i) { cum += hist[i]; if (cum >= need) { bs = i; break; } }
        bstar = bs;
    }
    __syncthreads();
    const int bs = bstar + 1;

    for (int i = tid; i < c; i += 256) {
        float d = cd[i];
        int bin = (int)((d - qq + 40.f) * 4.f);
        bin = bin < 0 ? 0 : (bin > 255 ? 255 : bin);
        if (bin <= bs) {
            int p = atomicAdd(&nsurv, 1);
            if (p < 512) sn[p] = cn[i];
        }
    }
    __syncthreads();
    int c2 = nsurv; if (c2 > 512) c2 = 512;

    const float qn = qsq_np;
    for (int i = tid; i < c2; i += 256) {
        const int n = sn[i];
        const float4* kr = (const float4*)(keys + ((size_t)a * N_N + n) * D_N);
        const float4* qr = (const float4*)qrow;
        float r[8];
#pragma unroll
        for (int j = 0; j < 8; ++j) r[j] = 0.f;
        float dot = 0.f;
#pragma unroll
        for (int cch = 0; cch < 16; ++cch) {
            float4 kk = kr[cch]; float4 qv = qr[cch];
            const int j0 = (cch & 1) * 4;
            if (cch < 2) {
                r[j0 + 0] = __fmul_rn(kk.x, kk.x);
                r[j0 + 1] = __fmul_rn(kk.y, kk.y);
                r[j0 + 2] = __fmul_rn(kk.z, kk.z);
                r[j0 + 3] = __fmul_rn(kk.w, kk.w);
            } else {
                r[j0 + 0] = __fadd_rn(r[j0 + 0], __fmul_rn(kk.x, kk.x));
                r[j0 + 1] = __fadd_rn(r[j0 + 1], __fmul_rn(kk.y, kk.y));
                r[j0 + 2] = __fadd_rn(r[j0 + 2], __fmul_rn(kk.z, kk.z));
                r[j0 + 3] = __fadd_rn(r[j0 + 3], __fmul_rn(kk.w, kk.w));
            }
            dot = __fmaf_rn(qv.x, kk.x, dot);
            dot = __fmaf_rn(qv.y, kk.y, dot);
            dot = __fmaf_rn(qv.z, kk.z, dot);
            dot = __fmaf_rn(qv.w, kk.w, dot);
        }
        const float ksq = np_tree8(r);
        sdf[i] = __fsub_rn(__fadd_rn(qn, ksq), __fmul_rn(2.0f, dot));
    }
    __syncthreads();

    for (int i = tid; i < c2; i += 256) {
        const float di = sdf[i]; const int ni = sn[i];
        int rank = 0;
        for (int j = 0; j < c2; ++j) {
            const float dj = sdf[j]; const int nj = sn[j];
            rank += (dj < di || (dj == di && nj < ni)) ? 1 : 0;
        }
        if (rank < K_N) wn[rank] = ni;
    }
    __syncthreads();

    if (tid < K_N) {
        const int n = wn[tid];
        const float* kr = keys + ((size_t)a * N_N + n) * D_N;
        float r[8];
#pragma unroll
        for (int j = 0; j < 8; ++j) {
            float d = __fsub_rn(qrow[j], kr[j]);
            r[j] = __fmul_rn(d, d);
        }
        for (int i = 8; i < 64; i += 8)
#pragma unroll
            for (int j = 0; j < 8; ++j) {
                float d = __fsub_rn(qrow[i + j], kr[i + j]);
                r[j] = __fadd_rn(r[j], __fmul_rn(d, d));
            }
        const float dist = np_tree8(r);
        wsc[tid] = dist;
        wgv[tid] = values[(size_t)a * N_N + n];
        dout[OFF_IDX + (size_t)(b * A_N + a) * K_N + tid] = (float)n;
        dout[OFF_SC  + (size_t)(b * A_N + a) * K_N + tid] = dist;
    }
    __syncthreads();

    if (tid == 0) {
        float w[K_N], wv[K_N];
#pragma unroll
        for (int k = 0; k < K_N; ++k) {
            w[k]  = __fdiv_rn(1.0f, __fadd_rn(wsc[k], 0.001f));
            wv[k] = __fmul_rn(w[k], wgv[k]);
        }
        const float s1 = np_sum50(w);
        const float s2 = np_sum50(wv);
        const float out = __fdiv_rn(s2, s1);
        vall[(size_t)b * A_N + a] = out;
        dout[OFF_VAL + b * A_N + a] = out;
    }
}

// ---------------------------------------------------------------------------
// K3: max / first-argmax over actions.
// ---------------------------------------------------------------------------
__global__ void dnd_k3(const float* __restrict__ vall, float* __restrict__ dout)
{
    const int b = threadIdx.x;
    float best = -__builtin_huge_valf(); int bi = 0;
#pragma unroll
    for (int a = 0; a < A_N; ++a) {
        const float v = vall[b * A_N + a];
        if (v > best) { best = v; bi = a; }
    }
    dout[OFF_MAX + b] = best;
    dout[OFF_ACT + b] = (float)bi;
}

extern "C" void kernel_launch(void* const* d_in, const int* in_sizes, int n_in,
                              void* d_out, int out_size, void* d_ws, size_t ws_size,
                              hipStream_t stream)
{
    (void)in_sizes; (void)n_in; (void)out_size;
    const float* query  = (const float*)d_in[0];
    const float* keys   = (const float*)d_in[1];
    const float* values = (const float*)d_in[2];
    float* dout = (float*)d_out;

    char*  ws    = (char*)d_ws;
    int*   cnt   = (int*)(ws + WS_CNT);
    float* vall  = (float*)(ws + WS_VALL);
    float* qsq_g = (float*)(ws + WS_QSQ);
    float* ksq_g = (float*)(ws + WS_KSQ);
    uint2* cand  = (uint2*)(ws + WS_CAND);

    int cap = CAPMAX;
    if (ws_size > WS_CAND) {
        size_t avail = (ws_size - WS_CAND) / ((size_t)A_N * B_N * 8);
        if ((size_t)cap > avail) cap = (int)avail;
    }
    if (cap < 1) cap = 1;

    hipMemsetAsync(cnt, 0, A_N * B_N * sizeof(int), stream);
    dnd_k0<<<(A_N * N_N + B_N + 255) / 256, 256, 0, stream>>>(query, keys, qsq_g, ksq_g);
    dim3 g1(SL, 2, A_N);
    dnd_k1<<<g1, 256, 0, stream>>>(query, keys, qsq_g, ksq_g, cnt, cand, cap);
    dim3 g2(B_N, A_N);
    dnd_k2<<<g2, 256, 0, stream>>>(query, keys, values, cnt, cand, cap, vall, dout);
    dnd_k3<<<1, 256, 0, stream>>>(vall, dout);
}

// Round 5
// 439.853 us; speedup vs baseline: 21.8911x; 1.7042x over previous
//
#include <hip/hip_runtime.h>
#include <cstdint>

// ---------------------------------------------------------------------------
// DND lookup: A=8, N=50000, D=64, B=256, K=50.
//   K0: row square-sums qsq[256], ksq[8*50000] (filter precision).
//   K1: bf16 MFMA filter GEMM (R4 was vector-fp32, latency-bound at 565us):
//       q/k tiles staged bf16 in MFMA-fragment order (reads = base+lane*16,
//       conflict-free), mfma_f32_16x16x32_bf16, epilogue inline per subtile.
//       d2 = qsq + ksq - 2*dot_bf16; noise <= ~0.3 << TMARG=25 margin.
//       Filter only — final ordering is K2's bit-exact fp32 np-replica.
//   K2: histogram-superset (margin widened +1 -> +4 bins = 1.0 d2 to absorb
//       bf16 filter noise) -> bit-exact numpy-fp32-replica re-score/rank.
//   K3: max / first-argmax.
// Output layout (flat fp32): [0,256) max | [256,512) action | [512,2560)
// values_all | [2560,104960) idx | [104960,207360) scores.
// ---------------------------------------------------------------------------

#define A_N 8
#define N_N 50000
#define D_N 64
#define B_N 256
#define K_N 50

constexpr int   QT  = 64;                   // q rows per block
constexpr int   NBT = 128;                  // n rows per tile
constexpr int   NT  = (N_N + NBT - 1) / NBT;  // 391
constexpr int   SL  = 32;                   // grid 32*4*8 = 1024 blocks
constexpr int   CAPMAX = 4096;
constexpr float TMARG = 25.0f;

constexpr int OFF_MAX = 0;
constexpr int OFF_ACT = 256;
constexpr int OFF_VAL = 512;
constexpr int OFF_IDX = 2560;
constexpr int OFF_SC  = 104960;

// workspace layout (bytes)
constexpr size_t WS_CNT  = 0;          // 2048 * 4
constexpr size_t WS_VALL = 8192;       // 2048 * 4
constexpr size_t WS_QSQ  = 16384;      // 256 * 4
constexpr size_t WS_KSQ  = 17408;      // 400000 * 4
constexpr size_t WS_CAND = 1617920;    // 2048 * cap * 8

typedef __attribute__((ext_vector_type(8))) short bf16x8;
typedef __attribute__((ext_vector_type(4))) float f32x4;

// fp32 -> bf16 RTNE (bit trick), pack 8 floats into 4 dwords
__device__ __forceinline__ unsigned bfr(float f)
{
    unsigned u = __float_as_uint(f);
    return (u + 0x7FFFu + ((u >> 16) & 1u)) >> 16;
}
__device__ __forceinline__ uint4 packbf8(const float* f)
{
    uint4 w;
    w.x = bfr(f[0]) | (bfr(f[1]) << 16);
    w.y = bfr(f[2]) | (bfr(f[3]) << 16);
    w.z = bfr(f[4]) | (bfr(f[5]) << 16);
    w.w = bfr(f[6]) | (bfr(f[7]) << 16);
    return w;
}

// ---------------------------------------------------------------------------
// numpy pairwise_sum replicas (bit-exact via _rn intrinsics) — used by K2.
// ---------------------------------------------------------------------------
__device__ __forceinline__ float np_tree8(const float r[8])
{
    return __fadd_rn(__fadd_rn(__fadd_rn(r[0], r[1]), __fadd_rn(r[2], r[3])),
                     __fadd_rn(__fadd_rn(r[4], r[5]), __fadd_rn(r[6], r[7])));
}

__device__ __forceinline__ float np_sumsq64(const float* __restrict__ a)
{
    float r[8];
#pragma unroll
    for (int j = 0; j < 8; ++j) r[j] = __fmul_rn(a[j], a[j]);
    for (int i = 8; i < 64; i += 8)
#pragma unroll
        for (int j = 0; j < 8; ++j)
            r[j] = __fadd_rn(r[j], __fmul_rn(a[i + j], a[i + j]));
    return np_tree8(r);
}

__device__ __forceinline__ float np_sum50(const float* __restrict__ a)
{
    float r[8];
#pragma unroll
    for (int j = 0; j < 8; ++j) r[j] = a[j];
    for (int i = 8; i < 48; i += 8)
#pragma unroll
        for (int j = 0; j < 8; ++j) r[j] = __fadd_rn(r[j], a[i + j]);
    float res = np_tree8(r);
    res = __fadd_rn(res, a[48]);
    res = __fadd_rn(res, a[49]);
    return res;
}

// ---------------------------------------------------------------------------
// K0: row square-sums (filter precision only).
// ---------------------------------------------------------------------------
__global__ __launch_bounds__(256)
void dnd_k0(const float* __restrict__ query, const float* __restrict__ keys,
            float* __restrict__ qsq_g, float* __restrict__ ksq_g)
{
    const int r = blockIdx.x * 256 + threadIdx.x;
    if (r >= A_N * N_N + B_N) return;
    const bool isk = r < A_N * N_N;
    const float4* s4 = (const float4*)(isk ? (keys + (size_t)r * D_N)
                                           : (query + (size_t)(r - A_N * N_N) * D_N));
    float s = 0.f;
#pragma unroll
    for (int i = 0; i < 16; ++i) {
        float4 v = s4[i];
        s += v.x * v.x + v.y * v.y + v.z * v.z + v.w * v.w;
    }
    if (isk) ksq_g[r] = s; else qsq_g[r - A_N * N_N] = s;
}

// ---------------------------------------------------------------------------
// K1: bf16-MFMA distance filter.
// Fragment layouts (verified, cdna_hip_programming.md §3/§5):
//   A (16x16x32): lane = quad*16 + m holds A[m][quad*8 + j], j=0..7
//   B:            lane = quad*16 + n holds B[n][quad*8 + j] (k-dim matched)
//   C/D:          lane holds D[quad*4 + reg][lane&15]
// LDS frag storage: [frag_id][lane] * 16B -> all reads base+lane*16.
// ---------------------------------------------------------------------------
__global__ __launch_bounds__(256, 4)
void dnd_k1(const float* __restrict__ query, const float* __restrict__ keys,
            const float* __restrict__ qsq_g, const float* __restrict__ ksq_g,
            int* __restrict__ cnt, uint2* __restrict__ cand, int cap)
{
    __shared__ __align__(16) uint4 afrag[4][2][64];   // [qtile][kh][lane] 8 KB
    __shared__ __align__(16) uint4 bfrag[8][2][64];   // [s][kh][lane]    16 KB
    __shared__ float qsqs[QT];
    __shared__ float ksqs[NBT];

    const int a    = blockIdx.z;
    const int q0   = blockIdx.y * QT;
    const int sl   = blockIdx.x;
    const int tid  = threadIdx.x;
    const int lane = tid & 63;
    const int wave = tid >> 6;
    const int quad = lane >> 4;
    const int nl   = lane & 15;

    // ---- stage Q tile once: thread t -> q row r=t&63, k-seg seg=t>>6 ----
    {
        const int r = tid & 63, seg = tid >> 6;       // seg covers k 16*seg..+15
        const float4* s4 = (const float4*)(query + (size_t)(q0 + r) * D_N + seg * 16);
        float4 fv[4];
#pragma unroll
        for (int i = 0; i < 4; ++i) fv[i] = s4[i];
        const float* f = (const float*)fv;
        const int qtile = r >> 4, m = r & 15, kh = seg >> 1;
        const int quadA = (seg & 1) * 2;
        afrag[qtile][kh][quadA * 16 + m]       = packbf8(f);      // k=seg*16+j
        afrag[qtile][kh][(quadA + 1) * 16 + m] = packbf8(f + 8);  // k=seg*16+8+j
    }
    if (tid < QT) qsqs[tid] = qsq_g[q0 + tid];

    for (int t = sl; t < NT; t += SL) {
        const int n0 = t * NBT;
        __syncthreads();   // prev-iter frag readers done
        // ---- stage K tile: thread t -> n row r=t>>1, k-half h=t&1 ----
        {
            const int r = tid >> 1, h = tid & 1;
            int n = n0 + r; if (n > N_N - 1) n = N_N - 1;   // clamp tail (masked via ksqs)
            const float4* s4 = (const float4*)(keys + ((size_t)a * N_N + n) * D_N + h * 32);
            float4 fv[8];
#pragma unroll
            for (int i = 0; i < 8; ++i) fv[i] = s4[i];
            const float* f = (const float*)fv;
            const int s = r >> 4, m = r & 15;
#pragma unroll
            for (int g = 0; g < 4; ++g)                     // k = h*32 + g*8 + j
                bfrag[s][h][g * 16 + m] = packbf8(f + g * 8);
        }
        if (tid < NBT)
            ksqs[tid] = (n0 + tid < N_N) ? ksq_g[(size_t)a * N_N + n0 + tid]
                                         : __builtin_huge_valf();
        __syncthreads();

        // ---- compute: wave w handles q-subtile w (16 q rows) x 128 n ----
        const bf16x8 aA = ((const bf16x8*)afrag)[(wave * 2 + 0) * 64 + lane];
        const bf16x8 aB = ((const bf16x8*)afrag)[(wave * 2 + 1) * 64 + lane];

#pragma unroll
        for (int s = 0; s < 8; ++s) {
            const bf16x8 b0 = ((const bf16x8*)bfrag)[(s * 2 + 0) * 64 + lane];
            const bf16x8 b1 = ((const bf16x8*)bfrag)[(s * 2 + 1) * 64 + lane];
            f32x4 c = {0.f, 0.f, 0.f, 0.f};
            c = __builtin_amdgcn_mfma_f32_16x16x32_bf16(aA, b0, c, 0, 0, 0);
            c = __builtin_amdgcn_mfma_f32_16x16x32_bf16(aB, b1, c, 0, 0, 0);

            // epilogue inline: lane holds D[quad*4+r][nl]
            const int   nn  = n0 + s * 16 + nl;
            const float ksq = ksqs[s * 16 + nl];
#pragma unroll
            for (int r = 0; r < 4; ++r) {
                const int   qr = wave * 16 + quad * 4 + r;
                const float qq = qsqs[qr];
                const float d2 = qq + ksq - 2.0f * c[r];
                if (d2 <= qq + TMARG) {            // inf tail never passes
                    const int b = q0 + qr;
                    const int p = atomicAdd(&cnt[a * B_N + b], 1);
                    if (p < cap) {
                        uint2 e; e.x = __float_as_uint(d2); e.y = (unsigned)nn;
                        cand[(size_t)(a * B_N + b) * cap + p] = e;
                    }
                }
            }
        }
    }
}

// ---------------------------------------------------------------------------
// K2: per-(a,b) np-fp32-replica top-50 + outputs (R3-passing logic; only
// the histogram margin widened +1 -> +4 bins for bf16 filter noise).
// ---------------------------------------------------------------------------
__global__ __launch_bounds__(256, 2)
void dnd_k2(const float* __restrict__ query, const float* __restrict__ keys,
            const float* __restrict__ values,
            const int* __restrict__ cnt, const uint2* __restrict__ cand, int cap,
            float* __restrict__ vall, float* __restrict__ dout)
{
    __shared__ __align__(16) float qrow[D_N];
    __shared__ float cd[CAPMAX];
    __shared__ int   cn[CAPMAX];
    __shared__ int   hist[256];
    __shared__ float sdf[512];
    __shared__ int   sn[512];
    __shared__ int   wn[K_N];
    __shared__ float wsc[K_N];
    __shared__ float wgv[K_N];
    __shared__ int   nsurv;
    __shared__ int   bstar;
    __shared__ float sqsq;
    __shared__ float qsq_np;

    const int b   = blockIdx.x;
    const int a   = blockIdx.y;
    const int ab  = a * B_N + b;
    const int tid = threadIdx.x;

    if (tid < D_N) qrow[tid] = query[(size_t)b * D_N + tid];
    hist[tid & 255] = 0;
    if (tid == 0) nsurv = 0;
    if (tid < K_N) wn[tid] = 0;
    __syncthreads();
    if (tid < 64) {
        float v = qrow[tid];
        float s = v * v;
#pragma unroll
        for (int m = 1; m < 64; m <<= 1) s += __shfl_xor(s, m, 64);
        if (tid == 0) sqsq = s;
    }
    if (tid == 0) qsq_np = np_sumsq64(qrow);
    __syncthreads();

    int c = cnt[ab]; if (c > cap) c = cap; if (c > CAPMAX) c = CAPMAX;
    const float qq = sqsq;

    for (int i = tid; i < c; i += 256) {
        uint2 e = cand[(size_t)ab * cap + i];
        float d = __uint_as_float(e.x);
        cd[i] = d; cn[i] = (int)e.y;
        int bin = (int)((d - qq + 40.f) * 4.f);
        bin = bin < 0 ? 0 : (bin > 255 ? 255 : bin);
        atomicAdd(&hist[bin], 1);
    }
    __syncthreads();
    if (tid == 0) {
        const int need = c < K_N ? c : K_N;
        int cum = 0, bs = 255;
        for (int i = 0; i < 256; ++i) { cum += hist[i]; if (cum >= need) { bs = i; break; } }
        bstar = bs;
    }
    __syncthreads();
    // +4 bins (=1.0 d2) margin: superset robust to bf16-MFMA filter noise
    // (|noise| <= ~0.3 on both boundary estimate and member values).
    const int bs = bstar + 4;

    for (int i = tid; i < c; i += 256) {
        float d = cd[i];
        int bin = (int)((d - qq + 40.f) * 4.f);
        bin = bin < 0 ? 0 : (bin > 255 ? 255 : bin);
        if (bin <= bs) {
            int p = atomicAdd(&nsurv, 1);
            if (p < 512) sn[p] = cn[i];
        }
    }
    __syncthreads();
    int c2 = nsurv; if (c2 > 512) c2 = 512;

    const float qn = qsq_np;
    for (int i = tid; i < c2; i += 256) {
        const int n = sn[i];
        const float4* kr = (const float4*)(keys + ((size_t)a * N_N + n) * D_N);
        const float4* qr = (const float4*)qrow;
        float r[8];
#pragma unroll
        for (int j = 0; j < 8; ++j) r[j] = 0.f;
        float dot = 0.f;
#pragma unroll
        for (int cch = 0; cch < 16; ++cch) {
            float4 kk = kr[cch]; float4 qv = qr[cch];
            const int j0 = (cch & 1) * 4;
            if (cch < 2) {
                r[j0 + 0] = __fmul_rn(kk.x, kk.x);
                r[j0 + 1] = __fmul_rn(kk.y, kk.y);
                r[j0 + 2] = __fmul_rn(kk.z, kk.z);
                r[j0 + 3] = __fmul_rn(kk.w, kk.w);
            } else {
                r[j0 + 0] = __fadd_rn(r[j0 + 0], __fmul_rn(kk.x, kk.x));
                r[j0 + 1] = __fadd_rn(r[j0 + 1], __fmul_rn(kk.y, kk.y));
                r[j0 + 2] = __fadd_rn(r[j0 + 2], __fmul_rn(kk.z, kk.z));
                r[j0 + 3] = __fadd_rn(r[j0 + 3], __fmul_rn(kk.w, kk.w));
            }
            dot = __fmaf_rn(qv.x, kk.x, dot);
            dot = __fmaf_rn(qv.y, kk.y, dot);
            dot = __fmaf_rn(qv.z, kk.z, dot);
            dot = __fmaf_rn(qv.w, kk.w, dot);
        }
        const float ksq = np_tree8(r);
        sdf[i] = __fsub_rn(__fadd_rn(qn, ksq), __fmul_rn(2.0f, dot));
    }
    __syncthreads();

    for (int i = tid; i < c2; i += 256) {
        const float di = sdf[i]; const int ni = sn[i];
        int rank = 0;
        for (int j = 0; j < c2; ++j) {
            const float dj = sdf[j]; const int nj = sn[j];
            rank += (dj < di || (dj == di && nj < ni)) ? 1 : 0;
        }
        if (rank < K_N) wn[rank] = ni;
    }
    __syncthreads();

    if (tid < K_N) {
        const int n = wn[tid];
        const float* kr = keys + ((size_t)a * N_N + n) * D_N;
        float r[8];
#pragma unroll
        for (int j = 0; j < 8; ++j) {
            float d = __fsub_rn(qrow[j], kr[j]);
            r[j] = __fmul_rn(d, d);
        }
        for (int i = 8; i < 64; i += 8)
#pragma unroll
            for (int j = 0; j < 8; ++j) {
                float d = __fsub_rn(qrow[i + j], kr[i + j]);
                r[j] = __fadd_rn(r[j], __fmul_rn(d, d));
            }
        const float dist = np_tree8(r);
        wsc[tid] = dist;
        wgv[tid] = values[(size_t)a * N_N + n];
        dout[OFF_IDX + (size_t)(b * A_N + a) * K_N + tid] = (float)n;
        dout[OFF_SC  + (size_t)(b * A_N + a) * K_N + tid] = dist;
    }
    __syncthreads();

    if (tid == 0) {
        float w[K_N], wv[K_N];
#pragma unroll
        for (int k = 0; k < K_N; ++k) {
            w[k]  = __fdiv_rn(1.0f, __fadd_rn(wsc[k], 0.001f));
            wv[k] = __fmul_rn(w[k], wgv[k]);
        }
        const float s1 = np_sum50(w);
        const float s2 = np_sum50(wv);
        const float out = __fdiv_rn(s2, s1);
        vall[(size_t)b * A_N + a] = out;
        dout[OFF_VAL + b * A_N + a] = out;
    }
}

// ---------------------------------------------------------------------------
// K3: max / first-argmax over actions.
// ---------------------------------------------------------------------------
__global__ void dnd_k3(const float* __restrict__ vall, float* __restrict__ dout)
{
    const int b = threadIdx.x;
    float best = -__builtin_huge_valf(); int bi = 0;
#pragma unroll
    for (int a = 0; a < A_N; ++a) {
        const float v = vall[b * A_N + a];
        if (v > best) { best = v; bi = a; }
    }
    dout[OFF_MAX + b] = best;
    dout[OFF_ACT + b] = (float)bi;
}

extern "C" void kernel_launch(void* const* d_in, const int* in_sizes, int n_in,
                              void* d_out, int out_size, void* d_ws, size_t ws_size,
                              hipStream_t stream)
{
    (void)in_sizes; (void)n_in; (void)out_size;
    const float* query  = (const float*)d_in[0];
    const float* keys   = (const float*)d_in[1];
    const float* values = (const float*)d_in[2];
    float* dout = (float*)d_out;

    char*  ws    = (char*)d_ws;
    int*   cnt   = (int*)(ws + WS_CNT);
    float* vall  = (float*)(ws + WS_VALL);
    float* qsq_g = (float*)(ws + WS_QSQ);
    float* ksq_g = (float*)(ws + WS_KSQ);
    uint2* cand  = (uint2*)(ws + WS_CAND);

    int cap = CAPMAX;
    if (ws_size > WS_CAND) {
        size_t avail = (ws_size - WS_CAND) / ((size_t)A_N * B_N * 8);
        if ((size_t)cap > avail) cap = (int)avail;
    }
    if (cap < 1) cap = 1;

    hipMemsetAsync(cnt, 0, A_N * B_N * sizeof(int), stream);
    dnd_k0<<<(A_N * N_N + B_N + 255) / 256, 256, 0, stream>>>(query, keys, qsq_g, ksq_g);
    dim3 g1(SL, 4, A_N);
    dnd_k1<<<g1, 256, 0, stream>>>(query, keys, qsq_g, ksq_g, cnt, cand, cap);
    dim3 g2(B_N, A_N);
    dnd_k2<<<g2, 256, 0, stream>>>(query, keys, values, cnt, cand, cap, vall, dout);
    dnd_k3<<<1, 256, 0, stream>>>(vall, dout);
}

// Round 6
// 423.474 us; speedup vs baseline: 22.7378x; 1.0387x over previous
//
#include <hip/hip_runtime.h>
#include <cstdint>

// ---------------------------------------------------------------------------
// DND lookup: A=8, N=50000, D=64, B=256, K=50.
// Full path (workspace permitting):
//   K0b: pack keys -> global bf16 fragment-order image kbf (51 MB) + dot
//        thresholds thr_n = (ksq-25)/2  (dot >= thr  <=>  d2 <= qq+25);
//        zeroes cnt.
//   K1:  MFMA filter GEMM; B-tiles staged via global_load_lds width-16
//        (no pack, no staging VGPRs); A-frags in registers; 6 blocks/CU.
//        Pass -> cand entry (d2q<<16 | n), d2q = (ksq-2dot+40)*1000.
//   K2:  per-(a,b): integer-bin histogram superset (+4 bins = 1.0 d2 margin
//        for bf16 noise) -> bit-exact numpy-fp32-replica re-score/rank.
//   K3:  max / first-argmax reading values_all from dout.
// Fallback path (small ws): R5 kernels verbatim (passed), SL 32->64.
// Output layout (flat fp32): [0,256) max | [256,512) action | [512,2560)
// values_all | [2560,104960) idx | [104960,207360) scores.
// ---------------------------------------------------------------------------

#define A_N 8
#define N_N 50000
#define D_N 64
#define B_N 256
#define K_N 50

constexpr int   QT  = 64;                     // q rows per block
constexpr int   NBT = 128;                    // n rows per tile
constexpr int   NT  = (N_N + NBT - 1) / NBT;  // 391
constexpr int   SL  = 48;                     // full-path slices: 48*4*8=1536
constexpr int   SLF = 64;                     // fallback slices: 64*4*8=2048
constexpr int   CAPMAX = 4096;
constexpr float TMARG = 25.0f;
constexpr int   NPAD = NT * NBT;              // 50048 (padded n per action)

constexpr int OFF_MAX = 0;
constexpr int OFF_ACT = 256;
constexpr int OFF_VAL = 512;
constexpr int OFF_IDX = 2560;
constexpr int OFF_SC  = 104960;

// ---- full-path workspace layout (bytes) ----
constexpr size_t WSF_CNT  = 0;                         // 2048*4
constexpr size_t WSF_THR  = 8192;                      // 8*50048*4 = 1601536
constexpr size_t WSF_KBF  = 1609728;                   // 8*391*16384 = 51249152
constexpr size_t WSF_CAND = 52858880;                  // 2048*cap*4

// ---- fallback workspace layout (R5 verbatim) ----
constexpr size_t WS_CNT  = 0;
constexpr size_t WS_VALL = 8192;
constexpr size_t WS_QSQ  = 16384;
constexpr size_t WS_KSQ  = 17408;
constexpr size_t WS_CAND = 1617920;

typedef __attribute__((ext_vector_type(8))) short bf16x8;
typedef __attribute__((ext_vector_type(4))) float f32x4;

__device__ __forceinline__ unsigned bfr(float f)
{
    unsigned u = __float_as_uint(f);
    return (u + 0x7FFFu + ((u >> 16) & 1u)) >> 16;
}
__device__ __forceinline__ uint4 packbf8(const float* f)
{
    uint4 w;
    w.x = bfr(f[0]) | (bfr(f[1]) << 16);
    w.y = bfr(f[2]) | (bfr(f[3]) << 16);
    w.z = bfr(f[4]) | (bfr(f[5]) << 16);
    w.w = bfr(f[6]) | (bfr(f[7]) << 16);
    return w;
}

// async global -> LDS, 16 B/lane (dest must be wave-uniform base + lane*16)
__device__ __forceinline__ void async16(void* lds, const void* g)
{
    __builtin_amdgcn_global_load_lds(
        (const __attribute__((address_space(1))) void*)g,
        (__attribute__((address_space(3))) void*)lds, 16, 0, 0);
}

// ---------------------------------------------------------------------------
// numpy pairwise_sum replicas (bit-exact via _rn intrinsics).
// ---------------------------------------------------------------------------
__device__ __forceinline__ float np_tree8(const float r[8])
{
    return __fadd_rn(__fadd_rn(__fadd_rn(r[0], r[1]), __fadd_rn(r[2], r[3])),
                     __fadd_rn(__fadd_rn(r[4], r[5]), __fadd_rn(r[6], r[7])));
}

__device__ __forceinline__ float np_sumsq64(const float* __restrict__ a)
{
    float r[8];
#pragma unroll
    for (int j = 0; j < 8; ++j) r[j] = __fmul_rn(a[j], a[j]);
    for (int i = 8; i < 64; i += 8)
#pragma unroll
        for (int j = 0; j < 8; ++j)
            r[j] = __fadd_rn(r[j], __fmul_rn(a[i + j], a[i + j]));
    return np_tree8(r);
}

__device__ __forceinline__ float np_sum50(const float* __restrict__ a)
{
    float r[8];
#pragma unroll
    for (int j = 0; j < 8; ++j) r[j] = a[j];
    for (int i = 8; i < 48; i += 8)
#pragma unroll
        for (int j = 0; j < 8; ++j) r[j] = __fadd_rn(r[j], a[i + j]);
    float res = np_tree8(r);
    res = __fadd_rn(res, a[48]);
    res = __fadd_rn(res, a[49]);
    return res;
}

// ===========================================================================
// FULL PATH
// ===========================================================================

// K0b: pack keys to bf16 fragment image + thresholds; zero cnt.
__global__ __launch_bounds__(256)
void dnd_k0b(const float* __restrict__ keys, float* __restrict__ thrn,
             uint4* __restrict__ kbf, int* __restrict__ cnt)
{
    __shared__ float khalf[NBT][2];
    const int t   = blockIdx.x;
    const int a   = blockIdx.y;
    const int tid = threadIdx.x;
    const int r   = tid >> 1, h = tid & 1;

    int n = t * NBT + r; if (n > N_N - 1) n = N_N - 1;   // clamp tail rows
    const float4* s4 = (const float4*)(keys + ((size_t)a * N_N + n) * D_N + h * 32);
    float4 fv[8];
#pragma unroll
    for (int i = 0; i < 8; ++i) fv[i] = s4[i];
    float ps = 0.f;
#pragma unroll
    for (int i = 0; i < 8; ++i)
        ps += fv[i].x * fv[i].x + fv[i].y * fv[i].y + fv[i].z * fv[i].z + fv[i].w * fv[i].w;
    khalf[r][h] = ps;

    // pack 4 fragments: frag (s*2+h), elements g*16+m, k = h*32 + g*8 + j
    const float* f = (const float*)fv;
    const int s = r >> 4, m = r & 15;
    uint4* dst = kbf + ((size_t)(a * NT + t) * 16 + (s * 2 + h)) * 64;
#pragma unroll
    for (int g = 0; g < 4; ++g) dst[g * 16 + m] = packbf8(f + g * 8);

    __syncthreads();
    if (tid < NBT) {
        const int nn = t * NBT + tid;
        float thr = __builtin_huge_valf();            // tail: never passes
        if (nn < N_N) {
            const float ks = khalf[tid][0] + khalf[tid][1];
            thr = 0.5f * (ks - TMARG);                // dot >= thr <=> d2 <= qq+25
        }
        thrn[(size_t)a * NPAD + t * NBT + tid] = thr;
    }
    if (t == 0) cnt[a * B_N + tid] = 0;
}

// K1: MFMA filter GEMM, async-staged pre-packed B fragments.
__global__ __launch_bounds__(256, 6)
void dnd_k1(const float* __restrict__ query, const uint4* __restrict__ kbf,
            const float* __restrict__ thrn,
            int* __restrict__ cnt, unsigned* __restrict__ cand, int cap)
{
    __shared__ __align__(16) uint4 afrag[4][2][64];   // 8 KB
    __shared__ __align__(16) uint4 bfrag[16][64];     // 16 KB
    __shared__ float thrs[NBT];

    const int a    = blockIdx.z;
    const int q0   = blockIdx.y * QT;
    const int sl   = blockIdx.x;
    const int tid  = threadIdx.x;
    const int lane = tid & 63;
    const int wave = tid >> 6;
    const int quad = lane >> 4;
    const int nl   = lane & 15;

    // stage Q tile once (identical mapping to R5, which passed)
    {
        const int r = tid & 63, seg = tid >> 6;       // seg = k 16*seg..+15
        const float4* s4 = (const float4*)(query + (size_t)(q0 + r) * D_N + seg * 16);
        float4 fv[4];
#pragma unroll
        for (int i = 0; i < 4; ++i) fv[i] = s4[i];
        const float* f = (const float*)fv;
        const int qtile = r >> 4, m = r & 15, kh = seg >> 1;
        const int quadA = (seg & 1) * 2;
        afrag[qtile][kh][quadA * 16 + m]       = packbf8(f);
        afrag[qtile][kh][(quadA + 1) * 16 + m] = packbf8(f + 8);
    }
    __syncthreads();
    const bf16x8 aA = ((const bf16x8*)afrag)[(wave * 2 + 0) * 64 + lane];
    const bf16x8 aB = ((const bf16x8*)afrag)[(wave * 2 + 1) * 64 + lane];

    for (int t = sl; t < NT; t += SL) {
        const int n0 = t * NBT;
        __syncthreads();   // prev-iter bfrag readers done
        {
            const char* src = (const char*)(kbf + (size_t)(a * NT + t) * 1024);
#pragma unroll
            for (int i = 0; i < 4; ++i) {
                const int off = i * 4096 + tid * 16;
                async16((char*)bfrag + off, src + off);
            }
        }
        if (tid < NBT) thrs[tid] = thrn[(size_t)a * NPAD + n0 + tid];
        __syncthreads();   // drains async DMA + thrs visible

#pragma unroll
        for (int s = 0; s < 8; ++s) {
            const bf16x8 b0 = ((const bf16x8*)bfrag)[(s * 2 + 0) * 64 + lane];
            const bf16x8 b1 = ((const bf16x8*)bfrag)[(s * 2 + 1) * 64 + lane];
            f32x4 c = {0.f, 0.f, 0.f, 0.f};
            c = __builtin_amdgcn_mfma_f32_16x16x32_bf16(aA, b0, c, 0, 0, 0);
            c = __builtin_amdgcn_mfma_f32_16x16x32_bf16(aB, b1, c, 0, 0, 0);

            const int   nn  = n0 + s * 16 + nl;
            const float thr = thrs[s * 16 + nl];
#pragma unroll
            for (int r = 0; r < 4; ++r) {
                if (c[r] >= thr) {                    // inf tail never passes
                    const int b = q0 + wave * 16 + quad * 4 + r;
                    const float d2rel = fmaf(-2.f, c[r], fmaf(2.f, thr, TMARG)); // ksq-2dot
                    int qv = (int)fmaf(d2rel, 1000.f, 40000.f);                  // (d2rel+40)*1000
                    qv = qv < 0 ? 0 : (qv > 65535 ? 65535 : qv);
                    const int p = atomicAdd(&cnt[a * B_N + b], 1);
                    if (p < cap)
                        cand[(size_t)(a * B_N + b) * cap + p] =
                            ((unsigned)qv << 16) | (unsigned)nn;
                }
            }
        }
    }
}

// K2 (full): per-(a,b) np-fp32-replica top-50 + outputs. 4-byte cand decode,
// integer bins (bin = d2q/250, width 0.25 d2); logic otherwise = passing R5.
__global__ __launch_bounds__(256)
void dnd_k2(const float* __restrict__ query, const float* __restrict__ keys,
            const float* __restrict__ values,
            const int* __restrict__ cnt, const unsigned* __restrict__ cand, int cap,
            float* __restrict__ dout)
{
    __shared__ __align__(16) float qrow[D_N];
    __shared__ int   hist[256];
    __shared__ float sdf[512];
    __shared__ int   sn[512];
    __shared__ int   wn[K_N];
    __shared__ float wsc[K_N];
    __shared__ float wgv[K_N];
    __shared__ int   nsurv;
    __shared__ int   bstar;
    __shared__ float qsq_np;

    const int b   = blockIdx.x;
    const int a   = blockIdx.y;
    const int ab  = a * B_N + b;
    const int tid = threadIdx.x;

    if (tid < D_N) qrow[tid] = query[(size_t)b * D_N + tid];
    hist[tid & 255] = 0;
    if (tid == 0) nsurv = 0;
    if (tid < K_N) wn[tid] = 0;
    __syncthreads();
    if (tid == 0) qsq_np = np_sumsq64(qrow);
    __syncthreads();

    int c = cnt[ab]; if (c > cap) c = cap;
    const unsigned* base = cand + (size_t)ab * cap;

    // phase A: histogram (integer bins)
    for (int i = tid; i < c; i += 256) {
        int bin = (int)(base[i] >> 16) / 250;
        bin = bin > 255 ? 255 : bin;
        atomicAdd(&hist[bin], 1);
    }
    __syncthreads();
    if (tid == 0) {
        const int need = c < K_N ? c : K_N;
        int cum = 0, bs = 255;
        for (int i = 0; i < 256; ++i) { cum += hist[i]; if (cum >= need) { bs = i; break; } }
        bstar = bs;
    }
    __syncthreads();
    const int bs = bstar + 4;   // +1.0 d2 margin: superset under bf16 noise

    // phase B: compact survivor indices (re-read global, L2-hot)
    for (int i = tid; i < c; i += 256) {
        const unsigned e = base[i];
        int bin = (int)(e >> 16) / 250;
        bin = bin > 255 ? 255 : bin;
        if (bin <= bs) {
            int p = atomicAdd(&nsurv, 1);
            if (p < 512) sn[p] = (int)(e & 0xFFFFu);
        }
    }
    __syncthreads();
    int c2 = nsurv; if (c2 > 512) c2 = 512;

    // phase C: bit-exact np-replica fp32 d2 per survivor
    const float qn = qsq_np;
    for (int i = tid; i < c2; i += 256) {
        const int n = sn[i];
        const float4* kr = (const float4*)(keys + ((size_t)a * N_N + n) * D_N);
        const float4* qr = (const float4*)qrow;
        float r[8];
#pragma unroll
        for (int j = 0; j < 8; ++j) r[j] = 0.f;
        float dot = 0.f;
#pragma unroll
        for (int cch = 0; cch < 16; ++cch) {
            float4 kk = kr[cch]; float4 qv = qr[cch];
            const int j0 = (cch & 1) * 4;
            if (cch < 2) {
                r[j0 + 0] = __fmul_rn(kk.x, kk.x);
                r[j0 + 1] = __fmul_rn(kk.y, kk.y);
                r[j0 + 2] = __fmul_rn(kk.z, kk.z);
                r[j0 + 3] = __fmul_rn(kk.w, kk.w);
            } else {
                r[j0 + 0] = __fadd_rn(r[j0 + 0], __fmul_rn(kk.x, kk.x));
                r[j0 + 1] = __fadd_rn(r[j0 + 1], __fmul_rn(kk.y, kk.y));
                r[j0 + 2] = __fadd_rn(r[j0 + 2], __fmul_rn(kk.z, kk.z));
                r[j0 + 3] = __fadd_rn(r[j0 + 3], __fmul_rn(kk.w, kk.w));
            }
            dot = __fmaf_rn(qv.x, kk.x, dot);
            dot = __fmaf_rn(qv.y, kk.y, dot);
            dot = __fmaf_rn(qv.z, kk.z, dot);
            dot = __fmaf_rn(qv.w, kk.w, dot);
        }
        const float ksq = np_tree8(r);
        sdf[i] = __fsub_rn(__fadd_rn(qn, ksq), __fmul_rn(2.0f, dot));
    }
    __syncthreads();

    // phase D: lexicographic (d2, idx) rank — lax.top_k tie semantics
    for (int i = tid; i < c2; i += 256) {
        const float di = sdf[i]; const int ni = sn[i];
        int rank = 0;
        for (int j = 0; j < c2; ++j) {
            const float dj = sdf[j]; const int nj = sn[j];
            rank += (dj < di || (dj == di && nj < ni)) ? 1 : 0;
        }
        if (rank < K_N) wn[rank] = ni;
    }
    __syncthreads();

    // phase E1: replica scores + idx outputs
    if (tid < K_N) {
        const int n = wn[tid];
        const float* kr = keys + ((size_t)a * N_N + n) * D_N;
        float r[8];
#pragma unroll
        for (int j = 0; j < 8; ++j) {
            float d = __fsub_rn(qrow[j], kr[j]);
            r[j] = __fmul_rn(d, d);
        }
        for (int i = 8; i < 64; i += 8)
#pragma unroll
            for (int j = 0; j < 8; ++j) {
                float d = __fsub_rn(qrow[i + j], kr[i + j]);
                r[j] = __fadd_rn(r[j], __fmul_rn(d, d));
            }
        const float dist = np_tree8(r);
        wsc[tid] = dist;
        wgv[tid] = values[(size_t)a * N_N + n];
        dout[OFF_IDX + (size_t)(b * A_N + a) * K_N + tid] = (float)n;
        dout[OFF_SC  + (size_t)(b * A_N + a) * K_N + tid] = dist;
    }
    __syncthreads();

    // phase E2: replica weighted value
    if (tid == 0) {
        float w[K_N], wv[K_N];
#pragma unroll
        for (int k = 0; k < K_N; ++k) {
            w[k]  = __fdiv_rn(1.0f, __fadd_rn(wsc[k], 0.001f));
            wv[k] = __fmul_rn(w[k], wgv[k]);
        }
        dout[OFF_VAL + b * A_N + a] = __fdiv_rn(np_sum50(wv), np_sum50(w));
    }
}

// K3: max / first-argmax over actions (reads values_all from dout).
__global__ void dnd_k3(float* __restrict__ dout)
{
    const int b = threadIdx.x;
    float best = -__builtin_huge_valf(); int bi = 0;
#pragma unroll
    for (int a = 0; a < A_N; ++a) {
        const float v = dout[OFF_VAL + b * A_N + a];
        if (v > best) { best = v; bi = a; }
    }
    dout[OFF_MAX + b] = best;
    dout[OFF_ACT + b] = (float)bi;
}

// ===========================================================================
// FALLBACK PATH — R5 kernels verbatim (passed), SL 32 -> 64 only.
// ===========================================================================

__global__ __launch_bounds__(256)
void dnd_k0f(const float* __restrict__ query, const float* __restrict__ keys,
             float* __restrict__ qsq_g, float* __restrict__ ksq_g)
{
    const int r = blockIdx.x * 256 + threadIdx.x;
    if (r >= A_N * N_N + B_N) return;
    const bool isk = r < A_N * N_N;
    const float4* s4 = (const float4*)(isk ? (keys + (size_t)r * D_N)
                                           : (query + (size_t)(r - A_N * N_N) * D_N));
    float s = 0.f;
#pragma unroll
    for (int i = 0; i < 16; ++i) {
        float4 v = s4[i];
        s += v.x * v.x + v.y * v.y + v.z * v.z + v.w * v.w;
    }
    if (isk) ksq_g[r] = s; else qsq_g[r - A_N * N_N] = s;
}

__global__ __launch_bounds__(256, 4)
void dnd_k1f(const float* __restrict__ query, const float* __restrict__ keys,
             const float* __restrict__ qsq_g, const float* __restrict__ ksq_g,
             int* __restrict__ cnt, uint2* __restrict__ cand, int cap)
{
    __shared__ __align__(16) uint4 afrag[4][2][64];
    __shared__ __align__(16) uint4 bfrag[8][2][64];
    __shared__ float qsqs[QT];
    __shared__ float ksqs[NBT];

    const int a    = blockIdx.z;
    const int q0   = blockIdx.y * QT;
    const int sl   = blockIdx.x;
    const int tid  = threadIdx.x;
    const int lane = tid & 63;
    const int wave = tid >> 6;
    const int quad = lane >> 4;
    const int nl   = lane & 15;

    {
        const int r = tid & 63, seg = tid >> 6;
        const float4* s4 = (const float4*)(query + (size_t)(q0 + r) * D_N + seg * 16);
        float4 fv[4];
#pragma unroll
        for (int i = 0; i < 4; ++i) fv[i] = s4[i];
        const float* f = (const float*)fv;
        const int qtile = r >> 4, m = r & 15, kh = seg >> 1;
        const int quadA = (seg & 1) * 2;
        afrag[qtile][kh][quadA * 16 + m]       = packbf8(f);
        afrag[qtile][kh][(quadA + 1) * 16 + m] = packbf8(f + 8);
    }
    if (tid < QT) qsqs[tid] = qsq_g[q0 + tid];

    for (int t = sl; t < NT; t += SLF) {
        const int n0 = t * NBT;
        __syncthreads();
        {
            const int r = tid >> 1, h = tid & 1;
            int n = n0 + r; if (n > N_N - 1) n = N_N - 1;
            const float4* s4 = (const float4*)(keys + ((size_t)a * N_N + n) * D_N + h * 32);
            float4 fv[8];
#pragma unroll
            for (int i = 0; i < 8; ++i) fv[i] = s4[i];
            const float* f = (const float*)fv;
            const int s = r >> 4, m = r & 15;
#pragma unroll
            for (int g = 0; g < 4; ++g)
                bfrag[s][h][g * 16 + m] = packbf8(f + g * 8);
        }
        if (tid < NBT)
            ksqs[tid] = (n0 + tid < N_N) ? ksq_g[(size_t)a * N_N + n0 + tid]
                                         : __builtin_huge_valf();
        __syncthreads();

        const bf16x8 aA = ((const bf16x8*)afrag)[(wave * 2 + 0) * 64 + lane];
        const bf16x8 aB = ((const bf16x8*)afrag)[(wave * 2 + 1) * 64 + lane];

#pragma unroll
        for (int s = 0; s < 8; ++s) {
            const bf16x8 b0 = ((const bf16x8*)bfrag)[(s * 2 + 0) * 64 + lane];
            const bf16x8 b1 = ((const bf16x8*)bfrag)[(s * 2 + 1) * 64 + lane];
            f32x4 c = {0.f, 0.f, 0.f, 0.f};
            c = __builtin_amdgcn_mfma_f32_16x16x32_bf16(aA, b0, c, 0, 0, 0);
            c = __builtin_amdgcn_mfma_f32_16x16x32_bf16(aB, b1, c, 0, 0, 0);

            const int   nn  = n0 + s * 16 + nl;
            const float ksq = ksqs[s * 16 + nl];
#pragma unroll
            for (int r = 0; r < 4; ++r) {
                const int   qr = wave * 16 + quad * 4 + r;
                const float qq = qsqs[qr];
                const float d2 = qq + ksq - 2.0f * c[r];
                if (d2 <= qq + TMARG) {
                    const int b = q0 + qr;
                    const int p = atomicAdd(&cnt[a * B_N + b], 1);
                    if (p < cap) {
                        uint2 e; e.x = __float_as_uint(d2); e.y = (unsigned)nn;
                        cand[(size_t)(a * B_N + b) * cap + p] = e;
                    }
                }
            }
        }
    }
}

__global__ __launch_bounds__(256, 2)
void dnd_k2f(const float* __restrict__ query, const float* __restrict__ keys,
             const float* __restrict__ values,
             const int* __restrict__ cnt, const uint2* __restrict__ cand, int cap,
             float* __restrict__ dout)
{
    __shared__ __align__(16) float qrow[D_N];
    __shared__ float cd[CAPMAX];
    __shared__ int   cn[CAPMAX];
    __shared__ int   hist[256];
    __shared__ float sdf[512];
    __shared__ int   sn[512];
    __shared__ int   wn[K_N];
    __shared__ float wsc[K_N];
    __shared__ float wgv[K_N];
    __shared__ int   nsurv;
    __shared__ int   bstar;
    __shared__ float sqsq;
    __shared__ float qsq_np;

    const int b   = blockIdx.x;
    const int a   = blockIdx.y;
    const int ab  = a * B_N + b;
    const int tid = threadIdx.x;

    if (tid < D_N) qrow[tid] = query[(size_t)b * D_N + tid];
    hist[tid & 255] = 0;
    if (tid == 0) nsurv = 0;
    if (tid < K_N) wn[tid] = 0;
    __syncthreads();
    if (tid < 64) {
        float v = qrow[tid];
        float s = v * v;
#pragma unroll
        for (int m = 1; m < 64; m <<= 1) s += __shfl_xor(s, m, 64);
        if (tid == 0) sqsq = s;
    }
    if (tid == 0) qsq_np = np_sumsq64(qrow);
    __syncthreads();

    int c = cnt[ab]; if (c > cap) c = cap; if (c > CAPMAX) c = CAPMAX;
    const float qq = sqsq;

    for (int i = tid; i < c; i += 256) {
        uint2 e = cand[(size_t)ab * cap + i];
        float d = __uint_as_float(e.x);
        cd[i] = d; cn[i] = (int)e.y;
        int bin = (int)((d - qq + 40.f) * 4.f);
        bin = bin < 0 ? 0 : (bin > 255 ? 255 : bin);
        atomicAdd(&hist[bin], 1);
    }
    __syncthreads();
    if (tid == 0) {
        const int need = c < K_N ? c : K_N;
        int cum = 0, bs = 255;
        for (int i = 0; i < 256; ++i) { cum += hist[i]; if (cum >= need) { bs = i; break; } }
        bstar = bs;
    }
    __syncthreads();
    const int bs = bstar + 4;

    for (int i = tid; i < c; i += 256) {
        float d = cd[i];
        int bin = (int)((d - qq + 40.f) * 4.f);
        bin = bin < 0 ? 0 : (bin > 255 ? 255 : bin);
        if (bin <= bs) {
            int p = atomicAdd(&nsurv, 1);
            if (p < 512) sn[p] = cn[i];
        }
    }
    __syncthreads();
    int c2 = nsurv; if (c2 > 512) c2 = 512;

    const float qn = qsq_np;
    for (int i = tid; i < c2; i += 256) {
        const int n = sn[i];
        const float4* kr = (const float4*)(keys + ((size_t)a * N_N + n) * D_N);
        const float4* qr = (const float4*)qrow;
        float r[8];
#pragma unroll
        for (int j = 0; j < 8; ++j) r[j] = 0.f;
        float dot = 0.f;
#pragma unroll
        for (int cch = 0; cch < 16; ++cch) {
            float4 kk = kr[cch]; float4 qv = qr[cch];
            const int j0 = (cch & 1) * 4;
            if (cch < 2) {
                r[j0 + 0] = __fmul_rn(kk.x, kk.x);
                r[j0 + 1] = __fmul_rn(kk.y, kk.y);
                r[j0 + 2] = __fmul_rn(kk.z, kk.z);
                r[j0 + 3] = __fmul_rn(kk.w, kk.w);
            } else {
                r[j0 + 0] = __fadd_rn(r[j0 + 0], __fmul_rn(kk.x, kk.x));
                r[j0 + 1] = __fadd_rn(r[j0 + 1], __fmul_rn(kk.y, kk.y));
                r[j0 + 2] = __fadd_rn(r[j0 + 2], __fmul_rn(kk.z, kk.z));
                r[j0 + 3] = __fadd_rn(r[j0 + 3], __fmul_rn(kk.w, kk.w));
            }
            dot = __fmaf_rn(qv.x, kk.x, dot);
            dot = __fmaf_rn(qv.y, kk.y, dot);
            dot = __fmaf_rn(qv.z, kk.z, dot);
            dot = __fmaf_rn(qv.w, kk.w, dot);
        }
        const float ksq = np_tree8(r);
        sdf[i] = __fsub_rn(__fadd_rn(qn, ksq), __fmul_rn(2.0f, dot));
    }
    __syncthreads();

    for (int i = tid; i < c2; i += 256) {
        const float di = sdf[i]; const int ni = sn[i];
        int rank = 0;
        for (int j = 0; j < c2; ++j) {
            const float dj = sdf[j]; const int nj = sn[j];
            rank += (dj < di || (dj == di && nj < ni)) ? 1 : 0;
        }
        if (rank < K_N) wn[rank] = ni;
    }
    __syncthreads();

    if (tid < K_N) {
        const int n = wn[tid];
        const float* kr = keys + ((size_t)a * N_N + n) * D_N;
        float r[8];
#pragma unroll
        for (int j = 0; j < 8; ++j) {
            float d = __fsub_rn(qrow[j], kr[j]);
            r[j] = __fmul_rn(d, d);
        }
        for (int i = 8; i < 64; i += 8)
#pragma unroll
            for (int j = 0; j < 8; ++j) {
                float d = __fsub_rn(qrow[i + j], kr[i + j]);
                r[j] = __fadd_rn(r[j], __fmul_rn(d, d));
            }
        const float dist = np_tree8(r);
        wsc[tid] = dist;
        wgv[tid] = values[(size_t)a * N_N + n];
        dout[OFF_IDX + (size_t)(b * A_N + a) * K_N + tid] = (float)n;
        dout[OFF_SC  + (size_t)(b * A_N + a) * K_N + tid] = dist;
    }
    __syncthreads();

    if (tid == 0) {
        float w[K_N], wv[K_N];
#pragma unroll
        for (int k = 0; k < K_N; ++k) {
            w[k]  = __fdiv_rn(1.0f, __fadd_rn(wsc[k], 0.001f));
            wv[k] = __fmul_rn(w[k], wgv[k]);
        }
        dout[OFF_VAL + b * A_N + a] = __fdiv_rn(np_sum50(wv), np_sum50(w));
    }
}

// ===========================================================================
extern "C" void kernel_launch(void* const* d_in, const int* in_sizes, int n_in,
                              void* d_out, int out_size, void* d_ws, size_t ws_size,
                              hipStream_t stream)
{
    (void)in_sizes; (void)n_in; (void)out_size;
    const float* query  = (const float*)d_in[0];
    const float* keys   = (const float*)d_in[1];
    const float* values = (const float*)d_in[2];
    float* dout = (float*)d_out;
    char*  ws   = (char*)d_ws;

    // full path iff workspace fits kbf + cap>=3072 candidate slots
    long long capf = 0;
    if (ws_size > WSF_CAND)
        capf = (long long)((ws_size - WSF_CAND) / ((size_t)A_N * B_N * 4));
    const bool full = capf >= 3072;

    if (full) {
        int cap = capf > CAPMAX ? CAPMAX : (int)capf;
        int*      cnt  = (int*)(ws + WSF_CNT);
        float*    thrn = (float*)(ws + WSF_THR);
        uint4*    kbf  = (uint4*)(ws + WSF_KBF);
        unsigned* cand = (unsigned*)(ws + WSF_CAND);

        dim3 g0(NT, A_N);
        dnd_k0b<<<g0, 256, 0, stream>>>(keys, thrn, kbf, cnt);
        dim3 g1(SL, 4, A_N);
        dnd_k1<<<g1, 256, 0, stream>>>(query, kbf, thrn, cnt, cand, cap);
        dim3 g2(B_N, A_N);
        dnd_k2<<<g2, 256, 0, stream>>>(query, keys, values, cnt, cand, cap, dout);
        dnd_k3<<<1, 256, 0, stream>>>(dout);
    } else {
        int*   cnt   = (int*)(ws + WS_CNT);
        float* qsq_g = (float*)(ws + WS_QSQ);
        float* ksq_g = (float*)(ws + WS_KSQ);
        uint2* cand  = (uint2*)(ws + WS_CAND);
        int cap = CAPMAX;
        if (ws_size > WS_CAND) {
            size_t avail = (ws_size - WS_CAND) / ((size_t)A_N * B_N * 8);
            if ((size_t)cap > avail) cap = (int)avail;
        }
        if (cap < 1) cap = 1;

        hipMemsetAsync(cnt, 0, A_N * B_N * sizeof(int), stream);
        dnd_k0f<<<(A_N * N_N + B_N + 255) / 256, 256, 0, stream>>>(query, keys, qsq_g, ksq_g);
        dim3 g1(SLF, 4, A_N);
        dnd_k1f<<<g1, 256, 0, stream>>>(query, keys, qsq_g, ksq_g, cnt, cand, cap);
        dim3 g2(B_N, A_N);
        dnd_k2f<<<g2, 256, 0, stream>>>(query, keys, values, cnt, cand, cap, dout);
        dnd_k3<<<1, 256, 0, stream>>>(dout);
    }
}

// Round 7
// 275.685 us; speedup vs baseline: 34.9271x; 1.5361x over previous
//
#include <hip/hip_runtime.h>
#include <cstdint>

// ---------------------------------------------------------------------------
// DND lookup: A=8, N=50000, D=64, B=256, K=50.
// Full path (workspace permitting):
//   K0b: pack keys -> global bf16 fragment-order image kbf (51 MB) + dot
//        thresholds thr_n = (ksq-25)/2; zeroes cnt.
//   K1:  MFMA filter GEMM. R6 was epilogue-bound: per-lane contended global
//        atomicAdd+dependent-store (~61k cyc/iter). Now: candidates staged in
//        LDS (per-b ds_add_rtn counters, SLOTS=20), flushed once per tile
//        iteration with ONE bulk global atomic per b + contiguous copy.
//   K2:  per-(a,b): integer-bin histogram superset (+4 bins = 1.0 d2 margin
//        for bf16 noise) -> bit-exact numpy-fp32-replica re-score/rank.
//   K3:  max / first-argmax.
// Fallback path (small ws): R5 kernels verbatim (passed).
// Output layout (flat fp32): [0,256) max | [256,512) action | [512,2560)
// values_all | [2560,104960) idx | [104960,207360) scores.
// ---------------------------------------------------------------------------

#define A_N 8
#define N_N 50000
#define D_N 64
#define B_N 256
#define K_N 50

constexpr int   QT  = 64;                     // q rows per block
constexpr int   NBT = 128;                    // n rows per tile
constexpr int   NT  = (N_N + NBT - 1) / NBT;  // 391
constexpr int   SL  = 40;                     // full path: 40*4*8=1280 = 5/CU
constexpr int   SLF = 64;                     // fallback slices
constexpr int   SLOTS = 20;                   // LDS cand slots per b per iter
constexpr int   CAPMAX = 4096;
constexpr float TMARG = 25.0f;
constexpr int   NPAD = NT * NBT;              // 50048

constexpr int OFF_MAX = 0;
constexpr int OFF_ACT = 256;
constexpr int OFF_VAL = 512;
constexpr int OFF_IDX = 2560;
constexpr int OFF_SC  = 104960;

// ---- full-path workspace layout (bytes) ----
constexpr size_t WSF_CNT  = 0;                         // 2048*4
constexpr size_t WSF_THR  = 8192;                      // 8*50048*4
constexpr size_t WSF_KBF  = 1609728;                   // 8*391*16384
constexpr size_t WSF_CAND = 52858880;                  // 2048*cap*4

// ---- fallback workspace layout ----
constexpr size_t WS_CNT  = 0;
constexpr size_t WS_QSQ  = 16384;
constexpr size_t WS_KSQ  = 17408;
constexpr size_t WS_CAND = 1617920;

typedef __attribute__((ext_vector_type(8))) short bf16x8;
typedef __attribute__((ext_vector_type(4))) float f32x4;

__device__ __forceinline__ unsigned bfr(float f)
{
    unsigned u = __float_as_uint(f);
    return (u + 0x7FFFu + ((u >> 16) & 1u)) >> 16;
}
__device__ __forceinline__ uint4 packbf8(const float* f)
{
    uint4 w;
    w.x = bfr(f[0]) | (bfr(f[1]) << 16);
    w.y = bfr(f[2]) | (bfr(f[3]) << 16);
    w.z = bfr(f[4]) | (bfr(f[5]) << 16);
    w.w = bfr(f[6]) | (bfr(f[7]) << 16);
    return w;
}

__device__ __forceinline__ void async16(void* lds, const void* g)
{
    __builtin_amdgcn_global_load_lds(
        (const __attribute__((address_space(1))) void*)g,
        (__attribute__((address_space(3))) void*)lds, 16, 0, 0);
}

// ---------------------------------------------------------------------------
// numpy pairwise_sum replicas (bit-exact via _rn intrinsics).
// ---------------------------------------------------------------------------
__device__ __forceinline__ float np_tree8(const float r[8])
{
    return __fadd_rn(__fadd_rn(__fadd_rn(r[0], r[1]), __fadd_rn(r[2], r[3])),
                     __fadd_rn(__fadd_rn(r[4], r[5]), __fadd_rn(r[6], r[7])));
}

__device__ __forceinline__ float np_sumsq64(const float* __restrict__ a)
{
    float r[8];
#pragma unroll
    for (int j = 0; j < 8; ++j) r[j] = __fmul_rn(a[j], a[j]);
    for (int i = 8; i < 64; i += 8)
#pragma unroll
        for (int j = 0; j < 8; ++j)
            r[j] = __fadd_rn(r[j], __fmul_rn(a[i + j], a[i + j]));
    return np_tree8(r);
}

__device__ __forceinline__ float np_sum50(const float* __restrict__ a)
{
    float r[8];
#pragma unroll
    for (int j = 0; j < 8; ++j) r[j] = a[j];
    for (int i = 8; i < 48; i += 8)
#pragma unroll
        for (int j = 0; j < 8; ++j) r[j] = __fadd_rn(r[j], a[i + j]);
    float res = np_tree8(r);
    res = __fadd_rn(res, a[48]);
    res = __fadd_rn(res, a[49]);
    return res;
}

// ===========================================================================
// FULL PATH
// ===========================================================================

__global__ __launch_bounds__(256)
void dnd_k0b(const float* __restrict__ keys, float* __restrict__ thrn,
             uint4* __restrict__ kbf, int* __restrict__ cnt)
{
    __shared__ float khalf[NBT][2];
    const int t   = blockIdx.x;
    const int a   = blockIdx.y;
    const int tid = threadIdx.x;
    const int r   = tid >> 1, h = tid & 1;

    int n = t * NBT + r; if (n > N_N - 1) n = N_N - 1;
    const float4* s4 = (const float4*)(keys + ((size_t)a * N_N + n) * D_N + h * 32);
    float4 fv[8];
#pragma unroll
    for (int i = 0; i < 8; ++i) fv[i] = s4[i];
    float ps = 0.f;
#pragma unroll
    for (int i = 0; i < 8; ++i)
        ps += fv[i].x * fv[i].x + fv[i].y * fv[i].y + fv[i].z * fv[i].z + fv[i].w * fv[i].w;
    khalf[r][h] = ps;

    const float* f = (const float*)fv;
    const int s = r >> 4, m = r & 15;
    uint4* dst = kbf + ((size_t)(a * NT + t) * 16 + (s * 2 + h)) * 64;
#pragma unroll
    for (int g = 0; g < 4; ++g) dst[g * 16 + m] = packbf8(f + g * 8);

    __syncthreads();
    if (tid < NBT) {
        const int nn = t * NBT + tid;
        float thr = __builtin_huge_valf();
        if (nn < N_N) {
            const float ks = khalf[tid][0] + khalf[tid][1];
            thr = 0.5f * (ks - TMARG);                // dot >= thr <=> d2 <= qq+25
        }
        thrn[(size_t)a * NPAD + t * NBT + tid] = thr;
    }
    if (t == 0) cnt[a * B_N + tid] = 0;
}

// K1: MFMA filter; LDS-staged candidates, bulk flush per iteration.
__global__ __launch_bounds__(256, 5)
void dnd_k1(const float* __restrict__ query, const uint4* __restrict__ kbf,
            const float* __restrict__ thrn,
            int* __restrict__ cnt, unsigned* __restrict__ cand, int cap)
{
    __shared__ __align__(16) uint4 afrag[4][2][64];   // 8 KB
    __shared__ __align__(16) uint4 bfrag[16][64];     // 16 KB
    __shared__ float    thrs[NBT];
    __shared__ int      lcnt[QT];                     // per-b LDS counters
    __shared__ unsigned lbuf[QT][SLOTS];              // 5 KB

    const int a    = blockIdx.z;
    const int q0   = blockIdx.y * QT;
    const int sl   = blockIdx.x;
    const int tid  = threadIdx.x;
    const int lane = tid & 63;
    const int wave = tid >> 6;
    const int quad = lane >> 4;
    const int nl   = lane & 15;

    // stage Q tile once (mapping verified in R5/R6)
    {
        const int r = tid & 63, seg = tid >> 6;
        const float4* s4 = (const float4*)(query + (size_t)(q0 + r) * D_N + seg * 16);
        float4 fv[4];
#pragma unroll
        for (int i = 0; i < 4; ++i) fv[i] = s4[i];
        const float* f = (const float*)fv;
        const int qtile = r >> 4, m = r & 15, kh = seg >> 1;
        const int quadA = (seg & 1) * 2;
        afrag[qtile][kh][quadA * 16 + m]       = packbf8(f);
        afrag[qtile][kh][(quadA + 1) * 16 + m] = packbf8(f + 8);
    }
    if (tid < QT) lcnt[tid] = 0;
    __syncthreads();
    const bf16x8 aA = ((const bf16x8*)afrag)[(wave * 2 + 0) * 64 + lane];
    const bf16x8 aB = ((const bf16x8*)afrag)[(wave * 2 + 1) * 64 + lane];

    for (int t = sl; t < NT; t += SL) {
        const int n0 = t * NBT;
        __syncthreads();   // prev-iter bfrag/lbuf readers done; lcnt reset visible
        {
            const char* src = (const char*)(kbf + (size_t)(a * NT + t) * 1024);
#pragma unroll
            for (int i = 0; i < 4; ++i) {
                const int off = i * 4096 + tid * 16;
                async16((char*)bfrag + off, src + off);
            }
        }
        if (tid < NBT) thrs[tid] = thrn[(size_t)a * NPAD + n0 + tid];
        __syncthreads();   // DMA drained + thrs visible

#pragma unroll
        for (int s = 0; s < 8; ++s) {
            const bf16x8 b0 = ((const bf16x8*)bfrag)[(s * 2 + 0) * 64 + lane];
            const bf16x8 b1 = ((const bf16x8*)bfrag)[(s * 2 + 1) * 64 + lane];
            f32x4 c = {0.f, 0.f, 0.f, 0.f};
            c = __builtin_amdgcn_mfma_f32_16x16x32_bf16(aA, b0, c, 0, 0, 0);
            c = __builtin_amdgcn_mfma_f32_16x16x32_bf16(aB, b1, c, 0, 0, 0);

            const int   nn  = n0 + s * 16 + nl;
            const float thr = thrs[s * 16 + nl];
#pragma unroll
            for (int r = 0; r < 4; ++r) {
                if (c[r] >= thr) {                    // inf tail never passes
                    const int bl = wave * 16 + quad * 4 + r;   // local b
                    const float d2rel = fmaf(-2.f, c[r], fmaf(2.f, thr, TMARG));
                    int qv = (int)fmaf(d2rel, 1000.f, 40000.f);
                    qv = qv < 0 ? 0 : (qv > 65535 ? 65535 : qv);
                    const unsigned entry = ((unsigned)qv << 16) | (unsigned)nn;
                    const int p = atomicAdd(&lcnt[bl], 1);     // LDS atomic
                    if (p < SLOTS) lbuf[bl][p] = entry;
                    else {                                      // rare overflow
                        const int gb = a * B_N + q0 + bl;
                        const int gp = atomicAdd(&cnt[gb], 1);
                        if (gp < cap) cand[(size_t)gb * cap + gp] = entry;
                    }
                }
            }
        }

        __syncthreads();   // all lbuf writes done
        if (tid < QT) {
            int m = lcnt[tid]; lcnt[tid] = 0;
            if (m > SLOTS) m = SLOTS;
            if (m > 0) {
                const int gb = a * B_N + q0 + tid;
                const int base = atomicAdd(&cnt[gb], m);  // ONE atomic per b
                unsigned* dst = cand + (size_t)gb * cap;
                for (int i = 0; i < m; ++i) {
                    const int p = base + i;
                    if (p < cap) dst[p] = lbuf[tid][i];
                }
            }
        }
        // loop-top barrier covers lcnt reset + lbuf reuse
    }
}

// K2 (full): per-(a,b) np-fp32-replica top-50 + outputs (unchanged from R6).
__global__ __launch_bounds__(256)
void dnd_k2(const float* __restrict__ query, const float* __restrict__ keys,
            const float* __restrict__ values,
            const int* __restrict__ cnt, const unsigned* __restrict__ cand, int cap,
            float* __restrict__ dout)
{
    __shared__ __align__(16) float qrow[D_N];
    __shared__ int   hist[256];
    __shared__ float sdf[512];
    __shared__ int   sn[512];
    __shared__ int   wn[K_N];
    __shared__ float wsc[K_N];
    __shared__ float wgv[K_N];
    __shared__ int   nsurv;
    __shared__ int   bstar;
    __shared__ float qsq_np;

    const int b   = blockIdx.x;
    const int a   = blockIdx.y;
    const int ab  = a * B_N + b;
    const int tid = threadIdx.x;

    if (tid < D_N) qrow[tid] = query[(size_t)b * D_N + tid];
    hist[tid & 255] = 0;
    if (tid == 0) nsurv = 0;
    if (tid < K_N) wn[tid] = 0;
    __syncthreads();
    if (tid == 0) qsq_np = np_sumsq64(qrow);
    __syncthreads();

    int c = cnt[ab]; if (c > cap) c = cap;
    const unsigned* base = cand + (size_t)ab * cap;

    for (int i = tid; i < c; i += 256) {
        int bin = (int)(base[i] >> 16) / 250;
        bin = bin > 255 ? 255 : bin;
        atomicAdd(&hist[bin], 1);
    }
    __syncthreads();
    if (tid == 0) {
        const int need = c < K_N ? c : K_N;
        int cum = 0, bs = 255;
        for (int i = 0; i < 256; ++i) { cum += hist[i]; if (cum >= need) { bs = i; break; } }
        bstar = bs;
    }
    __syncthreads();
    const int bs = bstar + 4;   // +1.0 d2 margin under bf16 noise

    for (int i = tid; i < c; i += 256) {
        const unsigned e = base[i];
        int bin = (int)(e >> 16) / 250;
        bin = bin > 255 ? 255 : bin;
        if (bin <= bs) {
            int p = atomicAdd(&nsurv, 1);
            if (p < 512) sn[p] = (int)(e & 0xFFFFu);
        }
    }
    __syncthreads();
    int c2 = nsurv; if (c2 > 512) c2 = 512;

    const float qn = qsq_np;
    for (int i = tid; i < c2; i += 256) {
        const int n = sn[i];
        const float4* kr = (const float4*)(keys + ((size_t)a * N_N + n) * D_N);
        const float4* qr = (const float4*)qrow;
        float r[8];
#pragma unroll
        for (int j = 0; j < 8; ++j) r[j] = 0.f;
        float dot = 0.f;
#pragma unroll
        for (int cch = 0; cch < 16; ++cch) {
            float4 kk = kr[cch]; float4 qv = qr[cch];
            const int j0 = (cch & 1) * 4;
            if (cch < 2) {
                r[j0 + 0] = __fmul_rn(kk.x, kk.x);
                r[j0 + 1] = __fmul_rn(kk.y, kk.y);
                r[j0 + 2] = __fmul_rn(kk.z, kk.z);
                r[j0 + 3] = __fmul_rn(kk.w, kk.w);
            } else {
                r[j0 + 0] = __fadd_rn(r[j0 + 0], __fmul_rn(kk.x, kk.x));
                r[j0 + 1] = __fadd_rn(r[j0 + 1], __fmul_rn(kk.y, kk.y));
                r[j0 + 2] = __fadd_rn(r[j0 + 2], __fmul_rn(kk.z, kk.z));
                r[j0 + 3] = __fadd_rn(r[j0 + 3], __fmul_rn(kk.w, kk.w));
            }
            dot = __fmaf_rn(qv.x, kk.x, dot);
            dot = __fmaf_rn(qv.y, kk.y, dot);
            dot = __fmaf_rn(qv.z, kk.z, dot);
            dot = __fmaf_rn(qv.w, kk.w, dot);
        }
        const float ksq = np_tree8(r);
        sdf[i] = __fsub_rn(__fadd_rn(qn, ksq), __fmul_rn(2.0f, dot));
    }
    __syncthreads();

    for (int i = tid; i < c2; i += 256) {
        const float di = sdf[i]; const int ni = sn[i];
        int rank = 0;
        for (int j = 0; j < c2; ++j) {
            const float dj = sdf[j]; const int nj = sn[j];
            rank += (dj < di || (dj == di && nj < ni)) ? 1 : 0;
        }
        if (rank < K_N) wn[rank] = ni;
    }
    __syncthreads();

    if (tid < K_N) {
        const int n = wn[tid];
        const float* kr = keys + ((size_t)a * N_N + n) * D_N;
        float r[8];
#pragma unroll
        for (int j = 0; j < 8; ++j) {
            float d = __fsub_rn(qrow[j], kr[j]);
            r[j] = __fmul_rn(d, d);
        }
        for (int i = 8; i < 64; i += 8)
#pragma unroll
            for (int j = 0; j < 8; ++j) {
                float d = __fsub_rn(qrow[i + j], kr[i + j]);
                r[j] = __fadd_rn(r[j], __fmul_rn(d, d));
            }
        const float dist = np_tree8(r);
        wsc[tid] = dist;
        wgv[tid] = values[(size_t)a * N_N + n];
        dout[OFF_IDX + (size_t)(b * A_N + a) * K_N + tid] = (float)n;
        dout[OFF_SC  + (size_t)(b * A_N + a) * K_N + tid] = dist;
    }
    __syncthreads();

    if (tid == 0) {
        float w[K_N], wv[K_N];
#pragma unroll
        for (int k = 0; k < K_N; ++k) {
            w[k]  = __fdiv_rn(1.0f, __fadd_rn(wsc[k], 0.001f));
            wv[k] = __fmul_rn(w[k], wgv[k]);
        }
        dout[OFF_VAL + b * A_N + a] = __fdiv_rn(np_sum50(wv), np_sum50(w));
    }
}

__global__ void dnd_k3(float* __restrict__ dout)
{
    const int b = threadIdx.x;
    float best = -__builtin_huge_valf(); int bi = 0;
#pragma unroll
    for (int a = 0; a < A_N; ++a) {
        const float v = dout[OFF_VAL + b * A_N + a];
        if (v > best) { best = v; bi = a; }
    }
    dout[OFF_MAX + b] = best;
    dout[OFF_ACT + b] = (float)bi;
}

// ===========================================================================
// FALLBACK PATH — R5 kernels verbatim (passed).
// ===========================================================================

__global__ __launch_bounds__(256)
void dnd_k0f(const float* __restrict__ query, const float* __restrict__ keys,
             float* __restrict__ qsq_g, float* __restrict__ ksq_g)
{
    const int r = blockIdx.x * 256 + threadIdx.x;
    if (r >= A_N * N_N + B_N) return;
    const bool isk = r < A_N * N_N;
    const float4* s4 = (const float4*)(isk ? (keys + (size_t)r * D_N)
                                           : (query + (size_t)(r - A_N * N_N) * D_N));
    float s = 0.f;
#pragma unroll
    for (int i = 0; i < 16; ++i) {
        float4 v = s4[i];
        s += v.x * v.x + v.y * v.y + v.z * v.z + v.w * v.w;
    }
    if (isk) ksq_g[r] = s; else qsq_g[r - A_N * N_N] = s;
}

__global__ __launch_bounds__(256, 4)
void dnd_k1f(const float* __restrict__ query, const float* __restrict__ keys,
             const float* __restrict__ qsq_g, const float* __restrict__ ksq_g,
             int* __restrict__ cnt, uint2* __restrict__ cand, int cap)
{
    __shared__ __align__(16) uint4 afrag[4][2][64];
    __shared__ __align__(16) uint4 bfrag[8][2][64];
    __shared__ float qsqs[QT];
    __shared__ float ksqs[NBT];

    const int a    = blockIdx.z;
    const int q0   = blockIdx.y * QT;
    const int sl   = blockIdx.x;
    const int tid  = threadIdx.x;
    const int lane = tid & 63;
    const int wave = tid >> 6;
    const int quad = lane >> 4;
    const int nl   = lane & 15;

    {
        const int r = tid & 63, seg = tid >> 6;
        const float4* s4 = (const float4*)(query + (size_t)(q0 + r) * D_N + seg * 16);
        float4 fv[4];
#pragma unroll
        for (int i = 0; i < 4; ++i) fv[i] = s4[i];
        const float* f = (const float*)fv;
        const int qtile = r >> 4, m = r & 15, kh = seg >> 1;
        const int quadA = (seg & 1) * 2;
        afrag[qtile][kh][quadA * 16 + m]       = packbf8(f);
        afrag[qtile][kh][(quadA + 1) * 16 + m] = packbf8(f + 8);
    }
    if (tid < QT) qsqs[tid] = qsq_g[q0 + tid];

    for (int t = sl; t < NT; t += SLF) {
        const int n0 = t * NBT;
        __syncthreads();
        {
            const int r = tid >> 1, h = tid & 1;
            int n = n0 + r; if (n > N_N - 1) n = N_N - 1;
            const float4* s4 = (const float4*)(keys + ((size_t)a * N_N + n) * D_N + h * 32);
            float4 fv[8];
#pragma unroll
            for (int i = 0; i < 8; ++i) fv[i] = s4[i];
            const float* f = (const float*)fv;
            const int s = r >> 4, m = r & 15;
#pragma unroll
            for (int g = 0; g < 4; ++g)
                bfrag[s][h][g * 16 + m] = packbf8(f + g * 8);
        }
        if (tid < NBT)
            ksqs[tid] = (n0 + tid < N_N) ? ksq_g[(size_t)a * N_N + n0 + tid]
                                         : __builtin_huge_valf();
        __syncthreads();

        const bf16x8 aA = ((const bf16x8*)afrag)[(wave * 2 + 0) * 64 + lane];
        const bf16x8 aB = ((const bf16x8*)afrag)[(wave * 2 + 1) * 64 + lane];

#pragma unroll
        for (int s = 0; s < 8; ++s) {
            const bf16x8 b0 = ((const bf16x8*)bfrag)[(s * 2 + 0) * 64 + lane];
            const bf16x8 b1 = ((const bf16x8*)bfrag)[(s * 2 + 1) * 64 + lane];
            f32x4 c = {0.f, 0.f, 0.f, 0.f};
            c = __builtin_amdgcn_mfma_f32_16x16x32_bf16(aA, b0, c, 0, 0, 0);
            c = __builtin_amdgcn_mfma_f32_16x16x32_bf16(aB, b1, c, 0, 0, 0);

            const int   nn  = n0 + s * 16 + nl;
            const float ksq = ksqs[s * 16 + nl];
#pragma unroll
            for (int r = 0; r < 4; ++r) {
                const int   qr = wave * 16 + quad * 4 + r;
                const float qq = qsqs[qr];
                const float d2 = qq + ksq - 2.0f * c[r];
                if (d2 <= qq + TMARG) {
                    const int b = q0 + qr;
                    const int p = atomicAdd(&cnt[a * B_N + b], 1);
                    if (p < cap) {
                        uint2 e; e.x = __float_as_uint(d2); e.y = (unsigned)nn;
                        cand[(size_t)(a * B_N + b) * cap + p] = e;
                    }
                }
            }
        }
    }
}

__global__ __launch_bounds__(256, 2)
void dnd_k2f(const float* __restrict__ query, const float* __restrict__ keys,
             const float* __restrict__ values,
             const int* __restrict__ cnt, const uint2* __restrict__ cand, int cap,
             float* __restrict__ dout)
{
    __shared__ __align__(16) float qrow[D_N];
    __shared__ float cd[CAPMAX];
    __shared__ int   cn[CAPMAX];
    __shared__ int   hist[256];
    __shared__ float sdf[512];
    __shared__ int   sn[512];
    __shared__ int   wn[K_N];
    __shared__ float wsc[K_N];
    __shared__ float wgv[K_N];
    __shared__ int   nsurv;
    __shared__ int   bstar;
    __shared__ float sqsq;
    __shared__ float qsq_np;

    const int b   = blockIdx.x;
    const int a   = blockIdx.y;
    const int ab  = a * B_N + b;
    const int tid = threadIdx.x;

    if (tid < D_N) qrow[tid] = query[(size_t)b * D_N + tid];
    hist[tid & 255] = 0;
    if (tid == 0) nsurv = 0;
    if (tid < K_N) wn[tid] = 0;
    __syncthreads();
    if (tid < 64) {
        float v = qrow[tid];
        float s = v * v;
#pragma unroll
        for (int m = 1; m < 64; m <<= 1) s += __shfl_xor(s, m, 64);
        if (tid == 0) sqsq = s;
    }
    if (tid == 0) qsq_np = np_sumsq64(qrow);
    __syncthreads();

    int c = cnt[ab]; if (c > cap) c = cap; if (c > CAPMAX) c = CAPMAX;
    const float qq = sqsq;

    for (int i = tid; i < c; i += 256) {
        uint2 e = cand[(size_t)ab * cap + i];
        float d = __uint_as_float(e.x);
        cd[i] = d; cn[i] = (int)e.y;
        int bin = (int)((d - qq + 40.f) * 4.f);
        bin = bin < 0 ? 0 : (bin > 255 ? 255 : bin);
        atomicAdd(&hist[bin], 1);
    }
    __syncthreads();
    if (tid == 0) {
        const int need = c < K_N ? c : K_N;
        int cum = 0, bs = 255;
        for (int i = 0; i < 256; ++i) { cum += hist[i]; if (cum >= need) { bs = i; break; } }
        bstar = bs;
    }
    __syncthreads();
    const int bs = bstar + 4;

    for (int i = tid; i < c; i += 256) {
        float d = cd[i];
        int bin = (int)((d - qq + 40.f) * 4.f);
        bin = bin < 0 ? 0 : (bin > 255 ? 255 : bin);
        if (bin <= bs) {
            int p = atomicAdd(&nsurv, 1);
            if (p < 512) sn[p] = cn[i];
        }
    }
    __syncthreads();
    int c2 = nsurv; if (c2 > 512) c2 = 512;

    const float qn = qsq_np;
    for (int i = tid; i < c2; i += 256) {
        const int n = sn[i];
        const float4* kr = (const float4*)(keys + ((size_t)a * N_N + n) * D_N);
        const float4* qr = (const float4*)qrow;
        float r[8];
#pragma unroll
        for (int j = 0; j < 8; ++j) r[j] = 0.f;
        float dot = 0.f;
#pragma unroll
        for (int cch = 0; cch < 16; ++cch) {
            float4 kk = kr[cch]; float4 qv = qr[cch];
            const int j0 = (cch & 1) * 4;
            if (cch < 2) {
                r[j0 + 0] = __fmul_rn(kk.x, kk.x);
                r[j0 + 1] = __fmul_rn(kk.y, kk.y);
                r[j0 + 2] = __fmul_rn(kk.z, kk.z);
                r[j0 + 3] = __fmul_rn(kk.w, kk.w);
            } else {
                r[j0 + 0] = __fadd_rn(r[j0 + 0], __fmul_rn(kk.x, kk.x));
                r[j0 + 1] = __fadd_rn(r[j0 + 1], __fmul_rn(kk.y, kk.y));
                r[j0 + 2] = __fadd_rn(r[j0 + 2], __fmul_rn(kk.z, kk.z));
                r[j0 + 3] = __fadd_rn(r[j0 + 3], __fmul_rn(kk.w, kk.w));
            }
            dot = __fmaf_rn(qv.x, kk.x, dot);
            dot = __fmaf_rn(qv.y, kk.y, dot);
            dot = __fmaf_rn(qv.z, kk.z, dot);
            dot = __fmaf_rn(qv.w, kk.w, dot);
        }
        const float ksq = np_tree8(r);
        sdf[i] = __fsub_rn(__fadd_rn(qn, ksq), __fmul_rn(2.0f, dot));
    }
    __syncthreads();

    for (int i = tid; i < c2; i += 256) {
        const float di = sdf[i]; const int ni = sn[i];
        int rank = 0;
        for (int j = 0; j < c2; ++j) {
            const float dj = sdf[j]; const int nj = sn[j];
            rank += (dj < di || (dj == di && nj < ni)) ? 1 : 0;
        }
        if (rank < K_N) wn[rank] = ni;
    }
    __syncthreads();

    if (tid < K_N) {
        const int n = wn[tid];
        const float* kr = keys + ((size_t)a * N_N + n) * D_N;
        float r[8];
#pragma unroll
        for (int j = 0; j < 8; ++j) {
            float d = __fsub_rn(qrow[j], kr[j]);
            r[j] = __fmul_rn(d, d);
        }
        for (int i = 8; i < 64; i += 8)
#pragma unroll
            for (int j = 0; j < 8; ++j) {
                float d = __fsub_rn(qrow[i + j], kr[i + j]);
                r[j] = __fadd_rn(r[j], __fmul_rn(d, d));
            }
        const float dist = np_tree8(r);
        wsc[tid] = dist;
        wgv[tid] = values[(size_t)a * N_N + n];
        dout[OFF_IDX + (size_t)(b * A_N + a) * K_N + tid] = (float)n;
        dout[OFF_SC  + (size_t)(b * A_N + a) * K_N + tid] = dist;
    }
    __syncthreads();

    if (tid == 0) {
        float w[K_N], wv[K_N];
#pragma unroll
        for (int k = 0; k < K_N; ++k) {
            w[k]  = __fdiv_rn(1.0f, __fadd_rn(wsc[k], 0.001f));
            wv[k] = __fmul_rn(w[k], wgv[k]);
        }
        dout[OFF_VAL + b * A_N + a] = __fdiv_rn(np_sum50(wv), np_sum50(w));
    }
}

// ===========================================================================
extern "C" void kernel_launch(void* const* d_in, const int* in_sizes, int n_in,
                              void* d_out, int out_size, void* d_ws, size_t ws_size,
                              hipStream_t stream)
{
    (void)in_sizes; (void)n_in; (void)out_size;
    const float* query  = (const float*)d_in[0];
    const float* keys   = (const float*)d_in[1];
    const float* values = (const float*)d_in[2];
    float* dout = (float*)d_out;
    char*  ws   = (char*)d_ws;

    long long capf = 0;
    if (ws_size > WSF_CAND)
        capf = (long long)((ws_size - WSF_CAND) / ((size_t)A_N * B_N * 4));
    const bool full = capf >= 3072;

    if (full) {
        int cap = capf > CAPMAX ? CAPMAX : (int)capf;
        int*      cnt  = (int*)(ws + WSF_CNT);
        float*    thrn = (float*)(ws + WSF_THR);
        uint4*    kbf  = (uint4*)(ws + WSF_KBF);
        unsigned* cand = (unsigned*)(ws + WSF_CAND);

        dim3 g0(NT, A_N);
        dnd_k0b<<<g0, 256, 0, stream>>>(keys, thrn, kbf, cnt);
        dim3 g1(SL, 4, A_N);
        dnd_k1<<<g1, 256, 0, stream>>>(query, kbf, thrn, cnt, cand, cap);
        dim3 g2(B_N, A_N);
        dnd_k2<<<g2, 256, 0, stream>>>(query, keys, values, cnt, cand, cap, dout);
        dnd_k3<<<1, 256, 0, stream>>>(dout);
    } else {
        int*   cnt   = (int*)(ws + WS_CNT);
        float* qsq_g = (float*)(ws + WS_QSQ);
        float* ksq_g = (float*)(ws + WS_KSQ);
        uint2* cand  = (uint2*)(ws + WS_CAND);
        int cap = CAPMAX;
        if (ws_size > WS_CAND) {
            size_t avail = (ws_size - WS_CAND) / ((size_t)A_N * B_N * 8);
            if ((size_t)cap > avail) cap = (int)avail;
        }
        if (cap < 1) cap = 1;

        hipMemsetAsync(cnt, 0, A_N * B_N * sizeof(int), stream);
        dnd_k0f<<<(A_N * N_N + B_N + 255) / 256, 256, 0, stream>>>(query, keys, qsq_g, ksq_g);
        dim3 g1(SLF, 4, A_N);
        dnd_k1f<<<g1, 256, 0, stream>>>(query, keys, qsq_g, ksq_g, cnt, cand, cap);
        dim3 g2(B_N, A_N);
        dnd_k2f<<<g2, 256, 0, stream>>>(query, keys, values, cnt, cand, cap, dout);
        dnd_k3<<<1, 256, 0, stream>>>(dout);
    }
}